// Round 14
// baseline (794.226 us; speedup 1.0000x reference)
//
#include <hip/hip_runtime.h>
#include <hip/hip_bf16.h>
#include <math.h>

#define S_N 50000
#define E_N 20000
#define K_N 128
#define D_N 128
#define NE_N 800000
#define B_N 8192
#define L_N 3
#define GATE_TILES (NE_N / 64)   // 12500 per polarity
#define NB_S 782   // ceil(50000/64)
#define NB_E 313   // ceil(20000/64)
#define BPAD 464   // scan reserve base: per bucket p = (v+BPAD+15)&~15 <= v+479
#define BSLACK 480 // allocation slack per bucket (strictly > 479)

typedef __attribute__((ext_vector_type(4))) float floatx4;
typedef __attribute__((ext_vector_type(8))) short short8v;

__device__ __forceinline__ unsigned short f2bf(float x) {
  unsigned int u = __float_as_uint(x);
  u += 0x7FFFu + ((u >> 16) & 1u);
  return (unsigned short)(u >> 16);
}
__device__ __forceinline__ float bf2f(unsigned short u) {
  return __uint_as_float(((unsigned int)u) << 16);
}
__device__ __forceinline__ float sigm(float z) { return 1.0f / (1.0f + __expf(-z)); }

// OCP e4m3fn, round-to-nearest-even, saturating
__device__ __forceinline__ unsigned char f2e4m3(float x) {
  unsigned int u = __float_as_uint(x);
  unsigned char s = (unsigned char)((u >> 24) & 0x80);
  int e = (int)((u >> 23) & 0xFF) - 127;
  unsigned int m = u & 0x7FFFFF;
  if (((u >> 23) & 0xFF) == 0) return s;
  if (e >= 9) return s | 0x7E;
  if (e < -10) return s;
  if (e >= -6) {
    unsigned int keep = m >> 20;
    unsigned int rest = m & 0xFFFFF;
    if (rest > 0x80000u || (rest == 0x80000u && (keep & 1))) keep++;
    if (keep == 8) { keep = 0; e++; if (e >= 9) return s | 0x7E; }
    unsigned char b = (unsigned char)(s | ((e + 7) << 3) | keep);
    if ((b & 0x7F) == 0x7F) b = s | 0x7E;
    return b;
  }
  int shift = -6 - e;
  unsigned int full = 0x800000u | m;
  unsigned int q = full >> (20 + shift);
  unsigned int rest = full & ((1u << (20 + shift)) - 1);
  unsigned int half = 1u << (19 + shift);
  if (rest > half || (rest == half && (q & 1))) q++;
  if (q == 8) return s | 0x08;
  return (unsigned char)(s | q);
}
__device__ __forceinline__ unsigned int pk4_fp8(float4 v) {
  return (unsigned int)f2e4m3(v.x) | ((unsigned int)f2e4m3(v.y) << 8) |
         ((unsigned int)f2e4m3(v.z) << 16) | ((unsigned int)f2e4m3(v.w) << 24);
}

// ---------------- prep: fp8 W1s, |pw|^T, keT ----------------
__global__ void prep_kernel(const float* __restrict__ W1_l1, const float* __restrict__ W1_l0,
                            const float* __restrict__ pw1, const float* __restrict__ pw2,
                            const float* __restrict__ pw3, const float* __restrict__ ke,
                            unsigned int* __restrict__ w1f8_1, unsigned int* __restrict__ w1f8_0,
                            float* __restrict__ pw1T, float* __restrict__ pw2T,
                            float* __restrict__ pw3a, float* __restrict__ keT) {
  int i = blockIdx.x * blockDim.x + threadIdx.x;
  if (i < 8192) { w1f8_1[i] = pk4_fp8(((const float4*)W1_l1)[i]); return; }
  i -= 8192;
  if (i < 8192) { w1f8_0[i] = pk4_fp8(((const float4*)W1_l0)[i]); return; }
  i -= 8192;
  if (i < 32768) { int d = i >> 8, j = i & 255; pw1T[i] = fabsf(pw1[j * 128 + d]); return; }
  i -= 32768;
  if (i < 32768) { int d = i >> 7, j = i & 127; pw2T[i] = fabsf(pw2[j * 256 + d]); return; }
  i -= 32768;
  if (i < 128) { pw3a[i] = fabsf(pw3[i]); return; }
  i -= 128;
  if (i < 16384) { int d = i >> 7, k = i & 127; keT[i] = ke[k * 128 + d]; return; }
}

// ---------------- init: bf16 tables (spmm) + fp8 tables (gate) + f32 sums ----------------
__global__ void init_bf_kernel(const float* __restrict__ se, const float* __restrict__ ee,
                               unsigned short* __restrict__ sbf, unsigned short* __restrict__ ebf,
                               unsigned int* __restrict__ sf8, unsigned int* __restrict__ ef8,
                               float* __restrict__ sS, float* __restrict__ eS) {
  int i = blockIdx.x * blockDim.x + threadIdx.x;
  const int nS4 = S_N * 32, nE4 = E_N * 32;
  if (i < nS4) {
    float4 v = ((const float4*)se)[i];
    ((float4*)sS)[i] = v;
    unsigned int lo = (unsigned int)f2bf(v.x) | ((unsigned int)f2bf(v.y) << 16);
    unsigned int hi = (unsigned int)f2bf(v.z) | ((unsigned int)f2bf(v.w) << 16);
    ((uint2*)sbf)[i] = make_uint2(lo, hi);
    sf8[i] = pk4_fp8(v);
    return;
  }
  i -= nS4;
  if (i < nE4) {
    float4 v = ((const float4*)ee)[i];
    ((float4*)eS)[i] = v;
    unsigned int lo = (unsigned int)f2bf(v.x) | ((unsigned int)f2bf(v.y) << 16);
    unsigned int hi = (unsigned int)f2bf(v.z) | ((unsigned int)f2bf(v.w) << 16);
    ((uint2*)ebf)[i] = make_uint2(lo, hi);
    ef8[i] = pk4_fp8(v);
  }
}

__global__ void zero_kernel(int* __restrict__ p, int n) {
  int i = blockIdx.x * blockDim.x + threadIdx.x;
  if (i < n) p[i] = 0;
}

// ------- histograms: combined S/E (for append) + per-polarity u (for gate perm) -------
__global__ __launch_bounds__(256)
void histB_kernel(const int* __restrict__ u1, const int* __restrict__ i1,
                  const int* __restrict__ u0, const int* __restrict__ i0,
                  int* __restrict__ gHistS, int* __restrict__ gHistE,
                  int* __restrict__ gH1, int* __restrict__ gH0) {
  __shared__ int hS[NB_S], hE[NB_E], h1[NB_S], h0[NB_S];
  int t = threadIdx.x;
  for (int b = t; b < NB_S; b += 256) { hS[b] = 0; h1[b] = 0; h0[b] = 0; }
  for (int b = t; b < NB_E; b += 256) hE[b] = 0;
  __syncthreads();
  int e0 = blockIdx.x * 2048;
  for (int k = 0; k < 8; ++k) {
    int e = e0 + k * 256 + t;
    if (e < NE_N) {
      int a = u1[e] >> 6, c = u0[e] >> 6;
      atomicAdd(&hS[a], 1);
      atomicAdd(&hS[c], 1);
      atomicAdd(&hE[i1[e] >> 6], 1);
      atomicAdd(&hE[i0[e] >> 6], 1);
      atomicAdd(&h1[a], 1);
      atomicAdd(&h0[c], 1);
    }
  }
  __syncthreads();
  for (int b = t; b < NB_S; b += 256) {
    if (hS[b]) atomicAdd(&gHistS[b], hS[b]);
    if (h1[b]) atomicAdd(&gH1[b], h1[b]);
    if (h0[b]) atomicAdd(&gH0[b], h0[b]);
  }
  for (int b = t; b < NB_E; b += 256) if (hE[b]) atomicAdd(&gHistE[b], hE[b]);
}

// ------- scan: 4 independent arrays (S+padded, E+padded, perm1, perm0) -------
__global__ __launch_bounds__(256)
void scan4_kernel(const int* __restrict__ gHistS, int* __restrict__ baseS,
                  int* __restrict__ curS, int* __restrict__ basePS,
                  const int* __restrict__ gHistE, int* __restrict__ baseE,
                  int* __restrict__ curE, int* __restrict__ basePE,
                  const int* __restrict__ gH1, int* __restrict__ base1, int* __restrict__ cur1,
                  const int* __restrict__ gH0, int* __restrict__ base0, int* __restrict__ cur0) {
  int w = threadIdx.x >> 6, l = threadIdx.x & 63;
  const int* src; int n; int* bs; int* cur; int* bsP;
  if (w == 0)      { src = gHistS; n = NB_S; bs = baseS; cur = curS; bsP = basePS; }
  else if (w == 1) { src = gHistE; n = NB_E; bs = baseE; cur = curE; bsP = basePE; }
  else if (w == 2) { src = gH1;    n = NB_S; bs = base1; cur = cur1; bsP = nullptr; }
  else             { src = gH0;    n = NB_S; bs = base0; cur = cur0; bsP = nullptr; }
  int carry = 0, carryP = 0;
  for (int base = 0; base < n; base += 64) {
    int i = base + l;
    int v = (i < n) ? src[i] : 0;
    int p = (i < n && bsP) ? ((v + BPAD + 15) & ~15) : 0;
    int x = v, y = p;
#pragma unroll
    for (int o = 1; o < 64; o <<= 1) {
      int xx = __shfl_up(x, o, 64);
      int yy = __shfl_up(y, o, 64);
      if (l >= o) { x += xx; y += yy; }
    }
    if (i < n) {
      int ex = carry + x - v;
      bs[i] = ex; cur[i] = ex;
      if (bsP) bsP[i] = carryP + y - p;
    }
    carry += __shfl(x, 63, 64);
    carryP += __shfl(y, 63, 64);
  }
  if (l == 0) { bs[n] = carry; if (bsP) bsP[n] = carryP; }
}

// ------- permute edges by u-bucket (both polarities), bucket-append -------
__global__ __launch_bounds__(256)
void permute_kernel(const int* __restrict__ u1, const int* __restrict__ i1,
                    const int* __restrict__ u0, const int* __restrict__ i0,
                    int* __restrict__ cur1, int* __restrict__ cur0,
                    int2* __restrict__ upi1, int* __restrict__ op1,
                    int2* __restrict__ upi0, int* __restrict__ op0) {
  __shared__ int h1[NB_S], h0[NB_S];
  int t = threadIdx.x;
  for (int b = t; b < NB_S; b += 256) { h1[b] = 0; h0[b] = 0; }
  __syncthreads();
  int e0 = blockIdx.x * 2048;
  for (int k = 0; k < 8; ++k) {
    int e = e0 + k * 256 + t;
    if (e < NE_N) {
      atomicAdd(&h1[u1[e] >> 6], 1);
      atomicAdd(&h0[u0[e] >> 6], 1);
    }
  }
  __syncthreads();
  for (int b = t; b < NB_S; b += 256) { int c = h1[b]; h1[b] = c ? atomicAdd(&cur1[b], c) : 0; }
  for (int b = t; b < NB_S; b += 256) { int c = h0[b]; h0[b] = c ? atomicAdd(&cur0[b], c) : 0; }
  __syncthreads();
  for (int k = 0; k < 8; ++k) {
    int e = e0 + k * 256 + t;
    if (e < NE_N) {
      int a = u1[e], c = u0[e];
      int j = atomicAdd(&h1[a >> 6], 1);
      upi1[j] = make_int2(a, i1[e]); op1[j] = e;
      j = atomicAdd(&h0[c >> 6], 1);
      upi0[j] = make_int2(c, i0[e]); op0[j] = e;
    }
  }
}

// ------- edge gate: u-sorted tiles, chunked XCD-affine mapping, coalesced logit writes -------
__global__ __launch_bounds__(512, 2)
void gate_kernel(const int2* __restrict__ upi1, const int2* __restrict__ upi0,
                 const unsigned char* __restrict__ sf8, const unsigned char* __restrict__ ef8,
                 const unsigned char* __restrict__ w1f8_1, const unsigned char* __restrict__ w1f8_0,
                 const float* __restrict__ b1_1, const float* __restrict__ w2_1,
                 const float* __restrict__ b2_1,
                 const float* __restrict__ b1_0, const float* __restrict__ w2_0,
                 const float* __restrict__ b2_0,
                 float* __restrict__ lgP1, float* __restrict__ lgP0) {
  __shared__ unsigned char Xl[64 * 272];
  __shared__ float plds[8][16];
  const int2* upi; const unsigned char* w1f8;
  const float *b1p, *w2p, *b2p; float* lg;
  if (blockIdx.x < 2048) {
    upi = upi1; w1f8 = w1f8_1; b1p = b1_1; w2p = w2_1; b2p = b2_1; lg = lgP1;
  } else {
    upi = upi0; w1f8 = w1f8_0; b1p = b1_0; w2p = w2_0; b2p = b2_0; lg = lgP0;
  }
  int bb = blockIdx.x & 2047;
  int chunk = (bb & 7) * 256 + (bb >> 3);   // XCD-affine: XCD x covers contiguous chunks
  int tBeg = chunk * 7;
  int tEnd = tBeg + 7; if (tEnd > GATE_TILES) tEnd = GATE_TILES;
  if (tBeg >= GATE_TILES) return;
  int t = threadIdx.x;
  int wv = t >> 6, l = t & 63;
  int sub = l & 15, grp = l >> 4;
  int nh = wv & 1, rg = wv >> 1;

  long bfrag[4][8];
#pragma unroll
  for (int nt = 0; nt < 4; ++nt) {
    int col = nh * 64 + nt * 16 + sub;
#pragma unroll
    for (int ks = 0; ks < 8; ++ks)
      bfrag[nt][ks] = *(const long*)&w1f8[(col << 8) + ks * 32 + grp * 8];
  }
  float b1v[4], w2v[4];
#pragma unroll
  for (int nt = 0; nt < 4; ++nt) {
    int col = nh * 64 + nt * 16 + sub;
    b1v[nt] = b1p[col];
    w2v[nt] = w2p[col];
  }
  float b2s = b2p[0];

  for (int tile = tBeg; tile < tEnd; ++tile) {
    int e0 = tile * 64;
    {  // stage: thread t -> edge el=t>>3, 32B chunk q; XOR-swizzled LDS chunk q^(el&7)
      int el = t >> 3, q = t & 7;
      int2 ui = upi[e0 + el];
      const unsigned char* srcrow = (q < 4)
          ? sf8 + (size_t)ui.x * 128 + q * 32
          : ef8 + (size_t)ui.y * 128 + (q - 4) * 32;
      int qs = q ^ (el & 7);
      uint4 c0 = ((const uint4*)srcrow)[0];
      uint4 c1 = ((const uint4*)srcrow)[1];
      *(uint4*)&Xl[el * 272 + qs * 32] = c0;
      *(uint4*)&Xl[el * 272 + qs * 32 + 16] = c1;
    }
    __syncthreads();

    floatx4 zero4 = {0.f, 0.f, 0.f, 0.f};
    floatx4 acc[4] = {zero4, zero4, zero4, zero4};
#pragma unroll
    for (int ks = 0; ks < 8; ++ks) {
      int row = rg * 16 + sub;
      long a = *(const long*)&Xl[row * 272 + ((ks ^ (sub & 7)) << 5) + grp * 8];
#pragma unroll
      for (int nt = 0; nt < 4; ++nt)
        acc[nt] = __builtin_amdgcn_mfma_f32_16x16x32_fp8_fp8(a, bfrag[nt][ks], acc[nt], 0, 0, 0);
    }
    float p0 = 0, p1 = 0, p2 = 0, p3 = 0;
#pragma unroll
    for (int nt = 0; nt < 4; ++nt) {
      float bb2 = b1v[nt], ww = w2v[nt];
      p0 += fmaxf(acc[nt][0] + bb2, 0.0f) * ww;
      p1 += fmaxf(acc[nt][1] + bb2, 0.0f) * ww;
      p2 += fmaxf(acc[nt][2] + bb2, 0.0f) * ww;
      p3 += fmaxf(acc[nt][3] + bb2, 0.0f) * ww;
    }
#pragma unroll
    for (int m = 1; m < 16; m <<= 1) {
      p0 += __shfl_xor(p0, m, 64);
      p1 += __shfl_xor(p1, m, 64);
      p2 += __shfl_xor(p2, m, 64);
      p3 += __shfl_xor(p3, m, 64);
    }
    if (sub < 4) {
      float pv = (sub == 0) ? p0 : (sub == 1) ? p1 : (sub == 2) ? p2 : p3;
      plds[wv][grp * 4 + sub] = pv;
    }
    __syncthreads();
    if (wv == 0)
      lg[e0 + l] = plds[(l >> 4) * 2][l & 15] + plds[(l >> 4) * 2 + 1][l & 15] + b2s;
    __syncthreads();
  }
}

// ------- gate finish (permuted order): vP = val[e] * (0.3*sigmoid((lg+g)/T)+0.7) -------
__global__ __launch_bounds__(256)
void gatefin_kernel(const float* __restrict__ lgP1, const float* __restrict__ lgP0,
                    const int* __restrict__ op1, const int* __restrict__ op0,
                    const float* __restrict__ ui1_val, const float* __restrict__ iu1_val,
                    const float* __restrict__ eps_ui1, const float* __restrict__ eps_iu1,
                    const float* __restrict__ ui0_val, const float* __restrict__ iu0_val,
                    const float* __restrict__ eps_ui0, const float* __restrict__ eps_iu0,
                    float* __restrict__ vP1ui, float* __restrict__ vP1iu,
                    float* __restrict__ vP0ui, float* __restrict__ vP0iu) {
  int j = blockIdx.x * 256 + threadIdx.x;
  if (j >= NE_N) return;
  float lg1 = lgP1[j], lg0 = lgP0[j];
  int e1 = op1[j], e0 = op0[j];
  float ep, g, s;
  ep = fminf(fmaxf(eps_ui1[e1], 1e-6f), 1.0f - 1e-6f);
  g = __logf(ep) - log1pf(-ep);
  s = 1.0f / (1.0f + __expf(-(lg1 + g) * 5.0f));
  vP1ui[j] = ui1_val[e1] * (0.3f * s + 0.7f);      // aliases lgP1 (same index, read-before-write)
  ep = fminf(fmaxf(eps_iu1[e1], 1e-6f), 1.0f - 1e-6f);
  g = __logf(ep) - log1pf(-ep);
  s = 1.0f / (1.0f + __expf(-(lg1 + g) * 5.0f));
  vP1iu[j] = iu1_val[e1] * (0.3f * s + 0.7f);
  ep = fminf(fmaxf(eps_ui0[e0], 1e-6f), 1.0f - 1e-6f);
  g = __logf(ep) - log1pf(-ep);
  s = 1.0f / (1.0f + __expf(-(lg0 + g) * 5.0f));
  vP0ui[j] = ui0_val[e0] * (0.3f * s + 0.7f);      // aliases lgP0
  ep = fminf(fmaxf(eps_iu0[e0], 1e-6f), 1.0f - 1e-6f);
  g = __logf(ep) - log1pf(-ep);
  s = 1.0f / (1.0f + __expf(-(lg0 + g) * 5.0f));
  vP0iu[j] = iu0_val[e0] * (0.3f * s + 0.7f);
}

// ------- bucket-append records from PERMUTED lists: x=(row&63)<<16|col, y=f32 val -------
__global__ __launch_bounds__(256)
void append_kernel(const int2* __restrict__ upi1, const int2* __restrict__ upi0,
                   const float* __restrict__ vP1ui, const float* __restrict__ vP1iu,
                   const float* __restrict__ vP0ui, const float* __restrict__ vP0iu,
                   int* __restrict__ gCurS, int* __restrict__ gCurE,
                   int2* __restrict__ recS, int2* __restrict__ recE) {
  __shared__ int hS[NB_S], hE[NB_E];
  int t = threadIdx.x;
  for (int b = t; b < NB_S; b += 256) hS[b] = 0;
  for (int b = t; b < NB_E; b += 256) hE[b] = 0;
  __syncthreads();
  int e0 = blockIdx.x * 2048;
  for (int k = 0; k < 8; ++k) {
    int j = e0 + k * 256 + t;
    if (j < NE_N) {
      int2 p1 = upi1[j]; int2 p0 = upi0[j];
      atomicAdd(&hS[p1.x >> 6], 1);
      atomicAdd(&hS[p0.x >> 6], 1);
      atomicAdd(&hE[p1.y >> 6], 1);
      atomicAdd(&hE[p0.y >> 6], 1);
    }
  }
  __syncthreads();
  for (int b = t; b < NB_S; b += 256) { int c = hS[b]; hS[b] = c ? atomicAdd(&gCurS[b], c) : 0; }
  for (int b = t; b < NB_E; b += 256) { int c = hE[b]; hE[b] = c ? atomicAdd(&gCurE[b], c) : 0; }
  __syncthreads();
  for (int k = 0; k < 8; ++k) {
    int j = e0 + k * 256 + t;
    if (j < NE_N) {
      int2 p1 = upi1[j]; int2 p0 = upi0[j];
      int a = p1.x, b = p1.y, c = p0.x, d = p0.y;
      int s;
      s = atomicAdd(&hS[a >> 6], 1); recS[s] = make_int2(((a & 63) << 16) | b, __float_as_int(vP1ui[j]));
      s = atomicAdd(&hE[b >> 6], 1); recE[s] = make_int2(((b & 63) << 16) | a, __float_as_int(vP1iu[j]));
      s = atomicAdd(&hS[c >> 6], 1); recS[s] = make_int2(((c & 63) << 16) | d, __float_as_int(vP0ui[j]));
      s = atomicAdd(&hE[d >> 6], 1); recE[s] = make_int2(((d & 63) << 16) | c, __float_as_int(vP0iu[j]));
    }
  }
}

// ---- per-bucket counting sort by dst ROW into padded per-row segments (once) ----
__global__ __launch_bounds__(256)
void sortRow_kernel(const int* __restrict__ baseIn, const int* __restrict__ basePad,
                    const int2* __restrict__ rin_all, int2* __restrict__ rout_all,
                    int* __restrict__ rowPtr, int* __restrict__ rowCnt8, int nRowsTot) {
  __shared__ int cntR[64], offR[64], curR[64];
  int b = blockIdx.x, t = threadIdx.x;
  int bi = baseIn[b], cnt = baseIn[b + 1] - bi;
  int bo = basePad[b];
  int row0 = b * 64;
  const int2* rin = rin_all + bi;
  int2* rout = rout_all + bo;
  if (t < 64) cntR[t] = 0;
  __syncthreads();
  for (int j = t; j < cnt; j += 256) atomicAdd(&cntR[(rin[j].x >> 16) & 63], 1);
  __syncthreads();
  if (t < 64) {
    int p = (cntR[t] + 7) & ~7;
    int x = p;
#pragma unroll
    for (int o = 1; o < 64; o <<= 1) { int y = __shfl_up(x, o, 64); if (t >= o) x += y; }
    int ex = x - p;
    offR[t] = ex; curR[t] = ex;
    if (row0 + t < nRowsTot) {
      rowPtr[row0 + t] = bo + ex;
      rowCnt8[row0 + t] = p >> 3;
    }
  }
  __syncthreads();
  for (int j = t; j < cnt; j += 256) {
    int2 rc = rin[j];
    int r = (rc.x >> 16) & 63;
    int slot = atomicAdd(&curR[r], 1);
    rout[slot] = make_int2(rc.x & 0xFFFF, rc.y);
  }
  __syncthreads();
  if (t < 64) {
    int c = cntR[t], p = (c + 7) & ~7, o = offR[t];
    for (int j = c; j < p; ++j) rout[o + j] = make_int2(0, 0);
  }
}

// ---- spmm CSR bf16 (proven): wave per dst row, 8 records in flight ----
__global__ __launch_bounds__(256)
void spmm_csr_kernel(const int* __restrict__ rowPtrS, const int* __restrict__ rowCnt8S,
                     const int2* __restrict__ rec2S,
                     const int* __restrict__ rowPtrE, const int* __restrict__ rowCnt8E,
                     const int2* __restrict__ rec2E,
                     const unsigned short* __restrict__ scur, const unsigned short* __restrict__ ecur,
                     unsigned short* __restrict__ snxt, unsigned short* __restrict__ enxt,
                     float* __restrict__ stuS, float* __restrict__ exeS) {
  int gw = (blockIdx.x * 256 + threadIdx.x) >> 6;
  int l = threadIdx.x & 63;
  int g = l >> 3, lane8 = l & 7;
  if (gw >= S_N + E_N) return;
  const int2* rec; const unsigned short* src; unsigned short* dst; float* sum;
  const int* rp; const int* rc8; int r;
  if (gw < S_N) { r = gw;       rp = rowPtrS; rc8 = rowCnt8S; rec = rec2S; src = ecur; dst = snxt; sum = stuS; }
  else          { r = gw - S_N; rp = rowPtrE; rc8 = rowCnt8E; rec = rec2E; src = scur; dst = enxt; sum = exeS; }
  int s0 = rp[r], n8 = rc8[r];
  float acc[16];
#pragma unroll
  for (int i = 0; i < 16; ++i) acc[i] = 0.f;
  for (int k = 0; k < n8; ++k) {
    int2 e = rec[s0 + k * 8 + g];
    float val = __int_as_float(e.y);
    const uint4* rowp = (const uint4*)(src + (size_t)e.x * 128);
    uint4 q0 = rowp[lane8 * 2];
    uint4 q1 = rowp[lane8 * 2 + 1];
#pragma unroll
    for (int i = 0; i < 4; ++i) {
      unsigned int w = ((const unsigned int*)&q0)[i];
      acc[2 * i]     = fmaf(val, bf2f((unsigned short)(w & 0xFFFF)), acc[2 * i]);
      acc[2 * i + 1] = fmaf(val, bf2f((unsigned short)(w >> 16)),    acc[2 * i + 1]);
    }
#pragma unroll
    for (int i = 0; i < 4; ++i) {
      unsigned int w = ((const unsigned int*)&q1)[i];
      acc[8 + 2 * i]     = fmaf(val, bf2f((unsigned short)(w & 0xFFFF)), acc[8 + 2 * i]);
      acc[8 + 2 * i + 1] = fmaf(val, bf2f((unsigned short)(w >> 16)),    acc[8 + 2 * i + 1]);
    }
  }
#pragma unroll
  for (int m = 8; m < 64; m <<= 1) {
#pragma unroll
    for (int i = 0; i < 16; ++i) acc[i] += __shfl_xor(acc[i], m, 64);
  }
  if (g == 0) {
    size_t base = (size_t)r * 128 + lane8 * 16;
    short8v o0, o1;
#pragma unroll
    for (int i = 0; i < 8; ++i) { o0[i] = (short)f2bf(acc[i]); o1[i] = (short)f2bf(acc[8 + i]); }
    *(short8v*)(dst + base) = o0;
    *(short8v*)(dst + base + 8) = o1;
    float4* sp = (float4*)(sum + base);
#pragma unroll
    for (int i = 0; i < 4; ++i) {
      float4 s = sp[i];
      s.x += acc[4 * i]; s.y += acc[4 * i + 1]; s.z += acc[4 * i + 2]; s.w += acc[4 * i + 3];
      sp[i] = s;
    }
  }
}

// ---------------- head 1 ----------------
__global__ __launch_bounds__(256)
void head1_kernel(const int* __restrict__ stu_id, const int* __restrict__ exer_id,
                  const float* __restrict__ kn, const float* __restrict__ stuS,
                  const float* __restrict__ exeS, const float* __restrict__ keT,
                  const float* __restrict__ stub, const float* __restrict__ exeb,
                  const float* __restrict__ disc, float* __restrict__ xbuf) {
  __shared__ float srw[4][128], erw[4][128];
  int wv = threadIdx.x >> 6, l = threadIdx.x & 63;
  int b = blockIdx.x * 4 + wv;
  int sid = stu_id[b], eid = exer_id[b];
  float2 sv = ((const float2*)(stuS + (size_t)sid * 128))[l];
  float2 ev = ((const float2*)(exeS + (size_t)eid * 128))[l];
  srw[wv][2 * l] = sv.x * 0.25f; srw[wv][2 * l + 1] = sv.y * 0.25f;
  erw[wv][2 * l] = ev.x * 0.25f; erw[wv][2 * l + 1] = ev.y * 0.25f;
  __syncthreads();
  float s0 = 0, s1 = 0, d0 = 0, d1 = 0;
  for (int d = 0; d < 128; ++d) {
    float sd = srw[wv][d], ed = erw[wv][d];
    float ka = keT[d * 128 + l], kb = keT[d * 128 + l + 64];
    s0 = fmaf(sd, ka, s0); s1 = fmaf(sd, kb, s1);
    d0 = fmaf(ed, ka, d0); d1 = fmaf(ed, kb, d1);
  }
  float sbv = stub[sid], ebv = exeb[eid];
  float edv = sigm(disc[eid]);
  float st0 = sigm(s0 + sbv), st1 = sigm(s1 + sbv);
  float df0 = sigm(d0 + ebv), df1 = sigm(d1 + ebv);
  xbuf[(size_t)b * 128 + l]      = edv * (st0 - df0) * kn[(size_t)b * 128 + l];
  xbuf[(size_t)b * 128 + l + 64] = edv * (st1 - df1) * kn[(size_t)b * 128 + l + 64];
}

// ---------------- head 2: PosLinear MLP ----------------
__global__ __launch_bounds__(256)
void head2_kernel(const float* __restrict__ xbuf, const float* __restrict__ pw1T,
                  const float* __restrict__ pb1, const float* __restrict__ pw2T,
                  const float* __restrict__ pb2, const float* __restrict__ pw3a,
                  const float* __restrict__ pb3, float* __restrict__ out) {
  __shared__ float xs[4][128], h1s[4][256], h2s[4][128];
  int wv = threadIdx.x >> 6, l = threadIdx.x & 63;
  int b = blockIdx.x * 4 + wv;
  xs[wv][l] = xbuf[(size_t)b * 128 + l];
  xs[wv][l + 64] = xbuf[(size_t)b * 128 + l + 64];
  __syncthreads();
#pragma unroll
  for (int q = 0; q < 4; ++q) {
    int j = q * 64 + l;
    float acc = 0.f;
    for (int d = 0; d < 128; ++d) acc = fmaf(xs[wv][d], pw1T[d * 256 + j], acc);
    h1s[wv][j] = sigm(acc + pb1[j]);
  }
  __syncthreads();
#pragma unroll
  for (int q = 0; q < 2; ++q) {
    int j = q * 64 + l;
    float acc = 0.f;
    for (int d = 0; d < 256; ++d) acc = fmaf(h1s[wv][d], pw2T[d * 128 + j], acc);
    h2s[wv][j] = sigm(acc + pb2[j]);
  }
  __syncthreads();
  float p = h2s[wv][l] * pw3a[l] + h2s[wv][l + 64] * pw3a[l + 64];
#pragma unroll
  for (int m = 1; m < 64; m <<= 1) p += __shfl_xor(p, m, 64);
  if (l == 0) out[b] = sigm(p + pb3[0]);
}

extern "C" void kernel_launch(void* const* d_in, const int* in_sizes, int n_in,
                              void* d_out, int out_size, void* d_ws, size_t ws_size,
                              hipStream_t stream) {
  const int*   stu_id  = (const int*)  d_in[0];
  const int*   exer_id = (const int*)  d_in[1];
  const float* kn_emb  = (const float*)d_in[2];
  const int*   ui1_u   = (const int*)  d_in[3];
  const int*   ui1_i   = (const int*)  d_in[4];
  const float* ui1_val = (const float*)d_in[5];
  const float* iu1_val = (const float*)d_in[6];
  const float* eps_ui1 = (const float*)d_in[7];
  const float* eps_iu1 = (const float*)d_in[8];
  const int*   ui0_u   = (const int*)  d_in[9];
  const int*   ui0_i   = (const int*)  d_in[10];
  const float* ui0_val = (const float*)d_in[11];
  const float* iu0_val = (const float*)d_in[12];
  const float* eps_ui0 = (const float*)d_in[13];
  const float* eps_iu0 = (const float*)d_in[14];
  const float* stu_emb = (const float*)d_in[15];
  const float* exe_emb = (const float*)d_in[16];
  const float* kno_emb = (const float*)d_in[17];
  const float* stu_b   = (const float*)d_in[18];
  const float* exe_b   = (const float*)d_in[19];
  const float* disc    = (const float*)d_in[20];
  const float* W1_l1   = (const float*)d_in[21];
  const float* b1_l1   = (const float*)d_in[22];
  const float* W2_l1   = (const float*)d_in[23];
  const float* b2_l1   = (const float*)d_in[24];
  const float* W1_l0   = (const float*)d_in[25];
  const float* b1_l0   = (const float*)d_in[26];
  const float* W2_l0   = (const float*)d_in[27];
  const float* b2_l0   = (const float*)d_in[28];
  const float* pw1     = (const float*)d_in[29];
  const float* pb1     = (const float*)d_in[30];
  const float* pw2     = (const float*)d_in[31];
  const float* pb2     = (const float*)d_in[32];
  const float* pw3     = (const float*)d_in[33];
  const float* pb3     = (const float*)d_in[34];
  float* out = (float*)d_out;
  (void)in_sizes; (void)n_in; (void)out_size; (void)ws_size;

  size_t off = 0;
  char* base = (char*)d_ws;
  auto carve = [&](size_t bytes) -> char* {
    char* p = base + off;
    off += (bytes + 255) & ~(size_t)255;
    return p;
  };
  unsigned int* w1f8_1 = (unsigned int*)carve(8192 * 4);
  unsigned int* w1f8_0 = (unsigned int*)carve(8192 * 4);
  float* pw1T = (float*)carve(32768 * 4);
  float* pw2T = (float*)carve(32768 * 4);
  float* pw3a = (float*)carve(128 * 4);
  float* keT  = (float*)carve(16384 * 4);
  // vblock (15.8 MB): holds upi1 (int2[NE]) | upi0 (int2[NE]) = 4*NE ints = 12.8 MB during
  // permute->append; later reused as padded sorted S records (2*NE + BSLACK*NB_S) int2.
  char* vblock = carve((size_t)2 * NE_N * 8 + (size_t)BSLACK * NB_S * 8);
  int2* upi1 = (int2*)vblock;
  int2* upi0 = (int2*)vblock + NE_N;
  unsigned short* stuBfA = (unsigned short*)carve((size_t)S_N * 128 * 2);
  // stuBfB (12.8 MB) is dead until spmm layer 0 -> holds op1|op0|vP1iu|vP0iu (4*NE ints, exact fit)
  unsigned short* stuBfB = (unsigned short*)carve((size_t)S_N * 128 * 2);
  int*   op1   = (int*)stuBfB;
  int*   op0   = (int*)stuBfB + NE_N;
  float* vP1iu = (float*)((int*)stuBfB + 2 * NE_N);
  float* vP0iu = (float*)((int*)stuBfB + 3 * NE_N);
  unsigned short* exeBfA = (unsigned short*)carve((size_t)E_N * 128 * 2);
  unsigned short* exeBfB = (unsigned short*)carve((size_t)E_N * 128 * 2);
  unsigned int* sf8 = (unsigned int*)carve((size_t)S_N * 32 * 4);
  unsigned int* ef8 = (unsigned int*)carve((size_t)E_N * 32 * 4);
  float* stuS = (float*)carve((size_t)S_N * 128 * 4);
  float* exeS = (float*)carve((size_t)E_N * 128 * 4);
  float* lgP1 = (float*)carve((size_t)NE_N * 4);   // also vP1ui (same-index alias in gatefin)
  float* lgP0 = (float*)carve((size_t)NE_N * 4);   // also vP0ui
  int* gHistS = (int*)carve((size_t)(NB_S + NB_E + 2 * NB_S) * 4);
  int* gHistE = gHistS + NB_S;
  int* gH1 = gHistE + NB_E;
  int* gH0 = gH1 + NB_S;
  int* baseSb  = (int*)carve((size_t)(NB_S + 1) * 4);
  int* baseEb  = (int*)carve((size_t)(NB_E + 1) * 4);
  int* basePSb = (int*)carve((size_t)(NB_S + 1) * 4);
  int* basePEb = (int*)carve((size_t)(NB_E + 1) * 4);
  int* gCurS  = (int*)carve((size_t)NB_S * 4);
  int* gCurE  = (int*)carve((size_t)NB_E * 4);
  int* base1  = (int*)carve((size_t)(NB_S + 1) * 4);
  int* cur1   = (int*)carve((size_t)NB_S * 4);
  int* base0  = (int*)carve((size_t)(NB_S + 1) * 4);
  int* cur0   = (int*)carve((size_t)NB_S * 4);
  int2* recS = (int2*)carve((size_t)2 * NE_N * 8 + (size_t)BSLACK * NB_E * 8);
  int2* recE = (int2*)carve((size_t)2 * NE_N * 8);
  int* rowPtrS  = (int*)carve((size_t)S_N * 4);
  int* rowCnt8S = (int*)carve((size_t)S_N * 4);
  int* rowPtrE  = (int*)carve((size_t)E_N * 4);
  int* rowCnt8E = (int*)carve((size_t)E_N * 4);
  float* xbuf = (float*)carve((size_t)B_N * 128 * 4);
  int2* rec2S = (int2*)vblock;   // upi data dead after append (stream-ordered)
  int2* rec2E = recS;            // recS dead after sortRow_S (stream-ordered)
  float* vP1ui = lgP1;
  float* vP0ui = lgP0;

  prep_kernel<<<(98432 + 255) / 256, 256, 0, stream>>>(W1_l1, W1_l0, pw1, pw2, pw3, kno_emb,
                                                       w1f8_1, w1f8_0, pw1T, pw2T, pw3a, keT);
  init_bf_kernel<<<(2240000 + 255) / 256, 256, 0, stream>>>(stu_emb, exe_emb, stuBfA, exeBfA,
                                                            sf8, ef8, stuS, exeS);
  zero_kernel<<<(NB_S + NB_E + 2 * NB_S + 255) / 256, 256, 0, stream>>>(gHistS,
                                                                        NB_S + NB_E + 2 * NB_S);
  histB_kernel<<<(NE_N + 2047) / 2048, 256, 0, stream>>>(ui1_u, ui1_i, ui0_u, ui0_i,
                                                         gHistS, gHistE, gH1, gH0);
  scan4_kernel<<<1, 256, 0, stream>>>(gHistS, baseSb, gCurS, basePSb,
                                      gHistE, baseEb, gCurE, basePEb,
                                      gH1, base1, cur1, gH0, base0, cur0);
  permute_kernel<<<(NE_N + 2047) / 2048, 256, 0, stream>>>(ui1_u, ui1_i, ui0_u, ui0_i,
                                                           cur1, cur0, upi1, op1, upi0, op0);
  gate_kernel<<<4096, 512, 0, stream>>>(upi1, upi0,
                                        (const unsigned char*)sf8, (const unsigned char*)ef8,
                                        (const unsigned char*)w1f8_1, (const unsigned char*)w1f8_0,
                                        b1_l1, W2_l1, b2_l1, b1_l0, W2_l0, b2_l0,
                                        lgP1, lgP0);
  gatefin_kernel<<<(NE_N + 255) / 256, 256, 0, stream>>>(lgP1, lgP0, op1, op0,
                                                         ui1_val, iu1_val, eps_ui1, eps_iu1,
                                                         ui0_val, iu0_val, eps_ui0, eps_iu0,
                                                         vP1ui, vP1iu, vP0ui, vP0iu);
  append_kernel<<<(NE_N + 2047) / 2048, 256, 0, stream>>>(upi1, upi0,
                                                          vP1ui, vP1iu, vP0ui, vP0iu,
                                                          gCurS, gCurE, recS, recE);
  sortRow_kernel<<<NB_S, 256, 0, stream>>>(baseSb, basePSb, recS, rec2S,
                                           rowPtrS, rowCnt8S, S_N);
  sortRow_kernel<<<NB_E, 256, 0, stream>>>(baseEb, basePEb, recE, rec2E,
                                           rowPtrE, rowCnt8E, E_N);
  const unsigned short* scur = stuBfA; const unsigned short* ecur = exeBfA;
  unsigned short* snxt = stuBfB; unsigned short* enxt = exeBfB;
  for (int layer = 0; layer < L_N; ++layer) {
    spmm_csr_kernel<<<(S_N + E_N + 3) / 4, 256, 0, stream>>>(
        rowPtrS, rowCnt8S, rec2S, rowPtrE, rowCnt8E, rec2E,
        scur, ecur, snxt, enxt, stuS, exeS);
    const unsigned short* t1 = scur; scur = snxt; snxt = (unsigned short*)t1;
    const unsigned short* t2 = ecur; ecur = enxt; enxt = (unsigned short*)t2;
  }
  head1_kernel<<<B_N / 4, 256, 0, stream>>>(stu_id, exer_id, kn_emb, stuS, exeS, keT,
                                            stu_b, exe_b, disc, xbuf);
  head2_kernel<<<B_N / 4, 256, 0, stream>>>(xbuf, pw1T, pb1, pw2T, pb2, pw3a, pb3, out);
}

// Round 15
// 692.925 us; speedup vs baseline: 1.1462x; 1.1462x over previous
//
#include <hip/hip_runtime.h>
#include <hip/hip_bf16.h>
#include <math.h>

#define S_N 50000
#define E_N 20000
#define K_N 128
#define D_N 128
#define NE_N 800000
#define B_N 8192
#define L_N 3
#define GATE_TILES (NE_N / 64)
#define NB_S 782   // ceil(50000/64)
#define NB_E 313   // ceil(20000/64)
#define BPAD 464   // scan reserve base: per bucket p = (v+BPAD+15)&~15 <= v+479
#define BSLACK 480 // allocation slack per bucket (strictly > 479)

typedef __attribute__((ext_vector_type(4))) float floatx4;
typedef __attribute__((ext_vector_type(8))) short short8v;

__device__ __forceinline__ unsigned short f2bf(float x) {
  unsigned int u = __float_as_uint(x);
  u += 0x7FFFu + ((u >> 16) & 1u);
  return (unsigned short)(u >> 16);
}
__device__ __forceinline__ float bf2f(unsigned short u) {
  return __uint_as_float(((unsigned int)u) << 16);
}
__device__ __forceinline__ float sigm(float z) { return 1.0f / (1.0f + __expf(-z)); }

// OCP e4m3fn, round-to-nearest-even, saturating
__device__ __forceinline__ unsigned char f2e4m3(float x) {
  unsigned int u = __float_as_uint(x);
  unsigned char s = (unsigned char)((u >> 24) & 0x80);
  int e = (int)((u >> 23) & 0xFF) - 127;
  unsigned int m = u & 0x7FFFFF;
  if (((u >> 23) & 0xFF) == 0) return s;
  if (e >= 9) return s | 0x7E;
  if (e < -10) return s;
  if (e >= -6) {
    unsigned int keep = m >> 20;
    unsigned int rest = m & 0xFFFFF;
    if (rest > 0x80000u || (rest == 0x80000u && (keep & 1))) keep++;
    if (keep == 8) { keep = 0; e++; if (e >= 9) return s | 0x7E; }
    unsigned char b = (unsigned char)(s | ((e + 7) << 3) | keep);
    if ((b & 0x7F) == 0x7F) b = s | 0x7E;
    return b;
  }
  int shift = -6 - e;
  unsigned int full = 0x800000u | m;
  unsigned int q = full >> (20 + shift);
  unsigned int rest = full & ((1u << (20 + shift)) - 1);
  unsigned int half = 1u << (19 + shift);
  if (rest > half || (rest == half && (q & 1))) q++;
  if (q == 8) return s | 0x08;
  return (unsigned char)(s | q);
}
__device__ __forceinline__ unsigned int pk4_fp8(float4 v) {
  return (unsigned int)f2e4m3(v.x) | ((unsigned int)f2e4m3(v.y) << 8) |
         ((unsigned int)f2e4m3(v.z) << 16) | ((unsigned int)f2e4m3(v.w) << 24);
}

// ---------------- prep: fp8 W1s, |pw|^T, keT ----------------
__global__ void prep_kernel(const float* __restrict__ W1_l1, const float* __restrict__ W1_l0,
                            const float* __restrict__ pw1, const float* __restrict__ pw2,
                            const float* __restrict__ pw3, const float* __restrict__ ke,
                            unsigned int* __restrict__ w1f8_1, unsigned int* __restrict__ w1f8_0,
                            float* __restrict__ pw1T, float* __restrict__ pw2T,
                            float* __restrict__ pw3a, float* __restrict__ keT) {
  int i = blockIdx.x * blockDim.x + threadIdx.x;
  if (i < 8192) { w1f8_1[i] = pk4_fp8(((const float4*)W1_l1)[i]); return; }
  i -= 8192;
  if (i < 8192) { w1f8_0[i] = pk4_fp8(((const float4*)W1_l0)[i]); return; }
  i -= 8192;
  if (i < 32768) { int d = i >> 8, j = i & 255; pw1T[i] = fabsf(pw1[j * 128 + d]); return; }
  i -= 32768;
  if (i < 32768) { int d = i >> 7, j = i & 127; pw2T[i] = fabsf(pw2[j * 256 + d]); return; }
  i -= 32768;
  if (i < 128) { pw3a[i] = fabsf(pw3[i]); return; }
  i -= 128;
  if (i < 16384) { int d = i >> 7, k = i & 127; keT[i] = ke[k * 128 + d]; return; }
}

// ---------------- init: bf16 tables (spmm) + fp8 tables (gate) + f32 sums ----------------
__global__ void init_bf_kernel(const float* __restrict__ se, const float* __restrict__ ee,
                               unsigned short* __restrict__ sbf, unsigned short* __restrict__ ebf,
                               unsigned int* __restrict__ sf8, unsigned int* __restrict__ ef8,
                               float* __restrict__ sS, float* __restrict__ eS) {
  int i = blockIdx.x * blockDim.x + threadIdx.x;
  const int nS4 = S_N * 32, nE4 = E_N * 32;
  if (i < nS4) {
    float4 v = ((const float4*)se)[i];
    ((float4*)sS)[i] = v;
    unsigned int lo = (unsigned int)f2bf(v.x) | ((unsigned int)f2bf(v.y) << 16);
    unsigned int hi = (unsigned int)f2bf(v.z) | ((unsigned int)f2bf(v.w) << 16);
    ((uint2*)sbf)[i] = make_uint2(lo, hi);
    sf8[i] = pk4_fp8(v);
    return;
  }
  i -= nS4;
  if (i < nE4) {
    float4 v = ((const float4*)ee)[i];
    ((float4*)eS)[i] = v;
    unsigned int lo = (unsigned int)f2bf(v.x) | ((unsigned int)f2bf(v.y) << 16);
    unsigned int hi = (unsigned int)f2bf(v.z) | ((unsigned int)f2bf(v.w) << 16);
    ((uint2*)ebf)[i] = make_uint2(lo, hi);
    ef8[i] = pk4_fp8(v);
  }
}

__global__ void zero_kernel(int* __restrict__ p, int n) {
  int i = blockIdx.x * blockDim.x + threadIdx.x;
  if (i < n) p[i] = 0;
}

// ---------------- bucket histogram (64-row buckets) ----------------
__global__ __launch_bounds__(256)
void histB_kernel(const int* __restrict__ u1, const int* __restrict__ i1,
                  const int* __restrict__ u0, const int* __restrict__ i0,
                  int* __restrict__ gHistS, int* __restrict__ gHistE) {
  __shared__ int hS[NB_S], hE[NB_E];
  int t = threadIdx.x;
  for (int b = t; b < NB_S; b += 256) hS[b] = 0;
  for (int b = t; b < NB_E; b += 256) hE[b] = 0;
  __syncthreads();
  int e0 = blockIdx.x * 2048;
  for (int k = 0; k < 8; ++k) {
    int e = e0 + k * 256 + t;
    if (e < NE_N) {
      atomicAdd(&hS[u1[e] >> 6], 1);
      atomicAdd(&hS[u0[e] >> 6], 1);
      atomicAdd(&hE[i1[e] >> 6], 1);
      atomicAdd(&hE[i0[e] >> 6], 1);
    }
  }
  __syncthreads();
  for (int b = t; b < NB_S; b += 256) if (hS[b]) atomicAdd(&gHistS[b], hS[b]);
  for (int b = t; b < NB_E; b += 256) if (hE[b]) atomicAdd(&gHistE[b], hE[b]);
}

// ------- scan buckets: packed bases+cursors AND padded-region bases -------
__global__ __launch_bounds__(128)
void scanB_kernel(const int* __restrict__ gHistS, int* __restrict__ baseS,
                  int* __restrict__ gCurS, int* __restrict__ basePS,
                  const int* __restrict__ gHistE, int* __restrict__ baseE,
                  int* __restrict__ gCurE, int* __restrict__ basePE) {
  int w = threadIdx.x >> 6, l = threadIdx.x & 63;
  int n = w ? NB_E : NB_S;
  const int* src = w ? gHistE : gHistS;
  int* bs  = w ? baseE  : baseS;
  int* cur = w ? gCurE  : gCurS;
  int* bsP = w ? basePE : basePS;
  int carry = 0, carryP = 0;
  for (int base = 0; base < n; base += 64) {
    int i = base + l;
    int v = (i < n) ? src[i] : 0;
    int p = (i < n) ? ((v + BPAD + 15) & ~15) : 0;
    int x = v, y = p;
#pragma unroll
    for (int o = 1; o < 64; o <<= 1) {
      int xx = __shfl_up(x, o, 64);
      int yy = __shfl_up(y, o, 64);
      if (l >= o) { x += xx; y += yy; }
    }
    if (i < n) {
      int ex = carry + x - v;
      bs[i] = ex; cur[i] = ex;
      bsP[i] = carryP + y - p;
    }
    carry += __shfl(x, 63, 64);
    carryP += __shfl(y, 63, 64);
  }
  if (l == 0) { bs[n] = carry; bsP[n] = carryP; }
}

// ------- edge gate: merged polarities, DOUBLE-BUFFERED (T14 async-stage) -------
__global__ __launch_bounds__(512, 2)
void gate_kernel(const int* __restrict__ eu1, const int* __restrict__ ei1,
                 const int* __restrict__ eu0, const int* __restrict__ ei0,
                 const unsigned char* __restrict__ sf8, const unsigned char* __restrict__ ef8,
                 const unsigned char* __restrict__ w1f8_1, const unsigned char* __restrict__ w1f8_0,
                 const float* __restrict__ b1_1, const float* __restrict__ w2_1,
                 const float* __restrict__ b2_1,
                 const float* __restrict__ b1_0, const float* __restrict__ w2_0,
                 const float* __restrict__ b2_0,
                 float* __restrict__ logit1, float* __restrict__ logit0) {
  __shared__ unsigned char Xl[2][64 * 272];
  __shared__ float plds[8][16];
  const int* eu; const int* ei; const unsigned char* w1f8;
  const float *b1p, *w2p, *b2p; float* lg;
  if (blockIdx.x < 2048) {
    eu = eu1; ei = ei1; w1f8 = w1f8_1; b1p = b1_1; w2p = w2_1; b2p = b2_1; lg = logit1;
  } else {
    eu = eu0; ei = ei0; w1f8 = w1f8_0; b1p = b1_0; w2p = w2_0; b2p = b2_0; lg = logit0;
  }
  int bb = blockIdx.x & 2047;
  int t = threadIdx.x;
  int wv = t >> 6, l = t & 63;
  int sub = l & 15, grp = l >> 4;
  int nh = wv & 1, rg = wv >> 1;
  int el = t >> 3, q = t & 7;

  long bfrag[4][8];
#pragma unroll
  for (int nt = 0; nt < 4; ++nt) {
    int col = nh * 64 + nt * 16 + sub;
#pragma unroll
    for (int ks = 0; ks < 8; ++ks)
      bfrag[nt][ks] = *(const long*)&w1f8[(col << 8) + ks * 32 + grp * 8];
  }
  float b1v[4], w2v[4];
#pragma unroll
  for (int nt = 0; nt < 4; ++nt) {
    int col = nh * 64 + nt * 16 + sub;
    b1v[nt] = b1p[col];
    w2v[nt] = w2p[col];
  }
  float b2s = b2p[0];

  uint4 c0, c1;
  {  // prologue: stage tile bb into buffer 0
    int eIdx = bb * 64 + el;
    const unsigned char* srcrow = (q < 4)
        ? sf8 + (size_t)eu[eIdx] * 128 + q * 32
        : ef8 + (size_t)ei[eIdx] * 128 + (q - 4) * 32;
    c0 = ((const uint4*)srcrow)[0];
    c1 = ((const uint4*)srcrow)[1];
    *(uint4*)&Xl[0][el * 272 + q * 32] = c0;
    *(uint4*)&Xl[0][el * 272 + q * 32 + 16] = c1;
  }
  int parity = 0;
  for (int tile = bb; tile < GATE_TILES; tile += 2048) {
    int nxt = tile + 2048;
    bool hasNext = (nxt < GATE_TILES);
    if (hasNext) {  // issue next tile's gathers early: latency hides under MFMA below
      int eIdx = nxt * 64 + el;
      const unsigned char* srcrow = (q < 4)
          ? sf8 + (size_t)eu[eIdx] * 128 + q * 32
          : ef8 + (size_t)ei[eIdx] * 128 + (q - 4) * 32;
      c0 = ((const uint4*)srcrow)[0];
      c1 = ((const uint4*)srcrow)[1];
    }
    __syncthreads();   // Xl[parity] fully staged

    floatx4 zero4 = {0.f, 0.f, 0.f, 0.f};
    floatx4 acc[4] = {zero4, zero4, zero4, zero4};
#pragma unroll
    for (int ks = 0; ks < 8; ++ks) {
      long a = *(const long*)&Xl[parity][(rg * 16 + sub) * 272 + ks * 32 + grp * 8];
#pragma unroll
      for (int nt = 0; nt < 4; ++nt)
        acc[nt] = __builtin_amdgcn_mfma_f32_16x16x32_fp8_fp8(a, bfrag[nt][ks], acc[nt], 0, 0, 0);
    }
    float p0 = 0, p1 = 0, p2 = 0, p3 = 0;
#pragma unroll
    for (int nt = 0; nt < 4; ++nt) {
      float bb2 = b1v[nt], ww = w2v[nt];
      p0 += fmaxf(acc[nt][0] + bb2, 0.0f) * ww;
      p1 += fmaxf(acc[nt][1] + bb2, 0.0f) * ww;
      p2 += fmaxf(acc[nt][2] + bb2, 0.0f) * ww;
      p3 += fmaxf(acc[nt][3] + bb2, 0.0f) * ww;
    }
#pragma unroll
    for (int m = 1; m < 16; m <<= 1) {
      p0 += __shfl_xor(p0, m, 64);
      p1 += __shfl_xor(p1, m, 64);
      p2 += __shfl_xor(p2, m, 64);
      p3 += __shfl_xor(p3, m, 64);
    }
    if (sub < 4) {
      float pv = (sub == 0) ? p0 : (sub == 1) ? p1 : (sub == 2) ? p2 : p3;
      plds[wv][grp * 4 + sub] = pv;
    }
    __syncthreads();   // plds ready; all reads of Xl[parity] done
    if (wv == 0)
      lg[tile * 64 + l] = plds[(l >> 4) * 2][l & 15] + plds[(l >> 4) * 2 + 1][l & 15] + b2s;
    if (hasNext) {     // write staged regs into the other buffer (its readers finished last iter)
      *(uint4*)&Xl[parity ^ 1][el * 272 + q * 32] = c0;
      *(uint4*)&Xl[parity ^ 1][el * 272 + q * 32 + 16] = c1;
    }
    parity ^= 1;
  }
}

// ------- append (gatefin FUSED): compute v inline from logit/eps/val, bucket-append -------
__global__ __launch_bounds__(256)
void append_kernel(const int* __restrict__ u1, const int* __restrict__ i1,
                   const int* __restrict__ u0, const int* __restrict__ i0,
                   const float* __restrict__ logit1, const float* __restrict__ logit0,
                   const float* __restrict__ ui1_val, const float* __restrict__ iu1_val,
                   const float* __restrict__ eps_ui1, const float* __restrict__ eps_iu1,
                   const float* __restrict__ ui0_val, const float* __restrict__ iu0_val,
                   const float* __restrict__ eps_ui0, const float* __restrict__ eps_iu0,
                   int* __restrict__ gCurS, int* __restrict__ gCurE,
                   int2* __restrict__ recS, int2* __restrict__ recE) {
  __shared__ int hS[NB_S], hE[NB_E];
  int t = threadIdx.x;
  for (int b = t; b < NB_S; b += 256) hS[b] = 0;
  for (int b = t; b < NB_E; b += 256) hE[b] = 0;
  __syncthreads();
  int e0 = blockIdx.x * 2048;
  for (int k = 0; k < 8; ++k) {
    int e = e0 + k * 256 + t;
    if (e < NE_N) {
      atomicAdd(&hS[u1[e] >> 6], 1);
      atomicAdd(&hS[u0[e] >> 6], 1);
      atomicAdd(&hE[i1[e] >> 6], 1);
      atomicAdd(&hE[i0[e] >> 6], 1);
    }
  }
  __syncthreads();
  for (int b = t; b < NB_S; b += 256) { int c = hS[b]; hS[b] = c ? atomicAdd(&gCurS[b], c) : 0; }
  for (int b = t; b < NB_E; b += 256) { int c = hE[b]; hE[b] = c ? atomicAdd(&gCurE[b], c) : 0; }
  __syncthreads();
  for (int k = 0; k < 8; ++k) {
    int e = e0 + k * 256 + t;
    if (e < NE_N) {
      int a = u1[e], b = i1[e], c = u0[e], d = i0[e];
      float lg1 = logit1[e], lg0 = logit0[e];
      float ep, g, s2;
      ep = fminf(fmaxf(eps_ui1[e], 1e-6f), 1.0f - 1e-6f);
      g = __logf(ep) - log1pf(-ep);
      s2 = 1.0f / (1.0f + __expf(-(lg1 + g) * 5.0f));
      float v_ui1 = ui1_val[e] * (0.3f * s2 + 0.7f);
      ep = fminf(fmaxf(eps_iu1[e], 1e-6f), 1.0f - 1e-6f);
      g = __logf(ep) - log1pf(-ep);
      s2 = 1.0f / (1.0f + __expf(-(lg1 + g) * 5.0f));
      float v_iu1 = iu1_val[e] * (0.3f * s2 + 0.7f);
      ep = fminf(fmaxf(eps_ui0[e], 1e-6f), 1.0f - 1e-6f);
      g = __logf(ep) - log1pf(-ep);
      s2 = 1.0f / (1.0f + __expf(-(lg0 + g) * 5.0f));
      float v_ui0 = ui0_val[e] * (0.3f * s2 + 0.7f);
      ep = fminf(fmaxf(eps_iu0[e], 1e-6f), 1.0f - 1e-6f);
      g = __logf(ep) - log1pf(-ep);
      s2 = 1.0f / (1.0f + __expf(-(lg0 + g) * 5.0f));
      float v_iu0 = iu0_val[e] * (0.3f * s2 + 0.7f);
      int s;
      s = atomicAdd(&hS[a >> 6], 1); recS[s] = make_int2(((a & 63) << 16) | b, __float_as_int(v_ui1));
      s = atomicAdd(&hE[b >> 6], 1); recE[s] = make_int2(((b & 63) << 16) | a, __float_as_int(v_iu1));
      s = atomicAdd(&hS[c >> 6], 1); recS[s] = make_int2(((c & 63) << 16) | d, __float_as_int(v_ui0));
      s = atomicAdd(&hE[d >> 6], 1); recE[s] = make_int2(((d & 63) << 16) | c, __float_as_int(v_iu0));
    }
  }
}

// ---- per-bucket counting sort by dst ROW into padded per-row segments (once) ----
__global__ __launch_bounds__(256)
void sortRow_kernel(const int* __restrict__ baseIn, const int* __restrict__ basePad,
                    const int2* __restrict__ rin_all, int2* __restrict__ rout_all,
                    int* __restrict__ rowPtr, int* __restrict__ rowCnt8, int nRowsTot) {
  __shared__ int cntR[64], offR[64], curR[64];
  int b = blockIdx.x, t = threadIdx.x;
  int bi = baseIn[b], cnt = baseIn[b + 1] - bi;
  int bo = basePad[b];
  int row0 = b * 64;
  const int2* rin = rin_all + bi;
  int2* rout = rout_all + bo;
  if (t < 64) cntR[t] = 0;
  __syncthreads();
  for (int j = t; j < cnt; j += 256) atomicAdd(&cntR[(rin[j].x >> 16) & 63], 1);
  __syncthreads();
  if (t < 64) {
    int p = (cntR[t] + 7) & ~7;
    int x = p;
#pragma unroll
    for (int o = 1; o < 64; o <<= 1) { int y = __shfl_up(x, o, 64); if (t >= o) x += y; }
    int ex = x - p;
    offR[t] = ex; curR[t] = ex;
    if (row0 + t < nRowsTot) {
      rowPtr[row0 + t] = bo + ex;
      rowCnt8[row0 + t] = p >> 3;
    }
  }
  __syncthreads();
  for (int j = t; j < cnt; j += 256) {
    int2 rc = rin[j];
    int r = (rc.x >> 16) & 63;
    int slot = atomicAdd(&curR[r], 1);
    rout[slot] = make_int2(rc.x & 0xFFFF, rc.y);
  }
  __syncthreads();
  if (t < 64) {
    int c = cntR[t], p = (c + 7) & ~7, o = offR[t];
    for (int j = c; j < p; ++j) rout[o + j] = make_int2(0, 0);
  }
}

// ---- spmm CSR bf16 (proven): wave per dst row, 8 records in flight ----
__global__ __launch_bounds__(256)
void spmm_csr_kernel(const int* __restrict__ rowPtrS, const int* __restrict__ rowCnt8S,
                     const int2* __restrict__ rec2S,
                     const int* __restrict__ rowPtrE, const int* __restrict__ rowCnt8E,
                     const int2* __restrict__ rec2E,
                     const unsigned short* __restrict__ scur, const unsigned short* __restrict__ ecur,
                     unsigned short* __restrict__ snxt, unsigned short* __restrict__ enxt,
                     float* __restrict__ stuS, float* __restrict__ exeS) {
  int gw = (blockIdx.x * 256 + threadIdx.x) >> 6;
  int l = threadIdx.x & 63;
  int g = l >> 3, lane8 = l & 7;
  if (gw >= S_N + E_N) return;
  const int2* rec; const unsigned short* src; unsigned short* dst; float* sum;
  const int* rp; const int* rc8; int r;
  if (gw < S_N) { r = gw;       rp = rowPtrS; rc8 = rowCnt8S; rec = rec2S; src = ecur; dst = snxt; sum = stuS; }
  else          { r = gw - S_N; rp = rowPtrE; rc8 = rowCnt8E; rec = rec2E; src = scur; dst = enxt; sum = exeS; }
  int s0 = rp[r], n8 = rc8[r];
  float acc[16];
#pragma unroll
  for (int i = 0; i < 16; ++i) acc[i] = 0.f;
  for (int k = 0; k < n8; ++k) {
    int2 e = rec[s0 + k * 8 + g];
    float val = __int_as_float(e.y);
    const uint4* rowp = (const uint4*)(src + (size_t)e.x * 128);
    uint4 q0 = rowp[lane8 * 2];
    uint4 q1 = rowp[lane8 * 2 + 1];
#pragma unroll
    for (int i = 0; i < 4; ++i) {
      unsigned int w = ((const unsigned int*)&q0)[i];
      acc[2 * i]     = fmaf(val, bf2f((unsigned short)(w & 0xFFFF)), acc[2 * i]);
      acc[2 * i + 1] = fmaf(val, bf2f((unsigned short)(w >> 16)),    acc[2 * i + 1]);
    }
#pragma unroll
    for (int i = 0; i < 4; ++i) {
      unsigned int w = ((const unsigned int*)&q1)[i];
      acc[8 + 2 * i]     = fmaf(val, bf2f((unsigned short)(w & 0xFFFF)), acc[8 + 2 * i]);
      acc[8 + 2 * i + 1] = fmaf(val, bf2f((unsigned short)(w >> 16)),    acc[8 + 2 * i + 1]);
    }
  }
#pragma unroll
  for (int m = 8; m < 64; m <<= 1) {
#pragma unroll
    for (int i = 0; i < 16; ++i) acc[i] += __shfl_xor(acc[i], m, 64);
  }
  if (g == 0) {
    size_t base = (size_t)r * 128 + lane8 * 16;
    short8v o0, o1;
#pragma unroll
    for (int i = 0; i < 8; ++i) { o0[i] = (short)f2bf(acc[i]); o1[i] = (short)f2bf(acc[8 + i]); }
    *(short8v*)(dst + base) = o0;
    *(short8v*)(dst + base + 8) = o1;
    float4* sp = (float4*)(sum + base);
#pragma unroll
    for (int i = 0; i < 4; ++i) {
      float4 s = sp[i];
      s.x += acc[4 * i]; s.y += acc[4 * i + 1]; s.z += acc[4 * i + 2]; s.w += acc[4 * i + 3];
      sp[i] = s;
    }
  }
}

// ---------------- head 1 ----------------
__global__ __launch_bounds__(256)
void head1_kernel(const int* __restrict__ stu_id, const int* __restrict__ exer_id,
                  const float* __restrict__ kn, const float* __restrict__ stuS,
                  const float* __restrict__ exeS, const float* __restrict__ keT,
                  const float* __restrict__ stub, const float* __restrict__ exeb,
                  const float* __restrict__ disc, float* __restrict__ xbuf) {
  __shared__ float srw[4][128], erw[4][128];
  int wv = threadIdx.x >> 6, l = threadIdx.x & 63;
  int b = blockIdx.x * 4 + wv;
  int sid = stu_id[b], eid = exer_id[b];
  float2 sv = ((const float2*)(stuS + (size_t)sid * 128))[l];
  float2 ev = ((const float2*)(exeS + (size_t)eid * 128))[l];
  srw[wv][2 * l] = sv.x * 0.25f; srw[wv][2 * l + 1] = sv.y * 0.25f;
  erw[wv][2 * l] = ev.x * 0.25f; erw[wv][2 * l + 1] = ev.y * 0.25f;
  __syncthreads();
  float s0 = 0, s1 = 0, d0 = 0, d1 = 0;
  for (int d = 0; d < 128; ++d) {
    float sd = srw[wv][d], ed = erw[wv][d];
    float ka = keT[d * 128 + l], kb = keT[d * 128 + l + 64];
    s0 = fmaf(sd, ka, s0); s1 = fmaf(sd, kb, s1);
    d0 = fmaf(ed, ka, d0); d1 = fmaf(ed, kb, d1);
  }
  float sbv = stub[sid], ebv = exeb[eid];
  float edv = sigm(disc[eid]);
  float st0 = sigm(s0 + sbv), st1 = sigm(s1 + sbv);
  float df0 = sigm(d0 + ebv), df1 = sigm(d1 + ebv);
  xbuf[(size_t)b * 128 + l]      = edv * (st0 - df0) * kn[(size_t)b * 128 + l];
  xbuf[(size_t)b * 128 + l + 64] = edv * (st1 - df1) * kn[(size_t)b * 128 + l + 64];
}

// ---------------- head 2: PosLinear MLP ----------------
__global__ __launch_bounds__(256)
void head2_kernel(const float* __restrict__ xbuf, const float* __restrict__ pw1T,
                  const float* __restrict__ pb1, const float* __restrict__ pw2T,
                  const float* __restrict__ pb2, const float* __restrict__ pw3a,
                  const float* __restrict__ pb3, float* __restrict__ out) {
  __shared__ float xs[4][128], h1s[4][256], h2s[4][128];
  int wv = threadIdx.x >> 6, l = threadIdx.x & 63;
  int b = blockIdx.x * 4 + wv;
  xs[wv][l] = xbuf[(size_t)b * 128 + l];
  xs[wv][l + 64] = xbuf[(size_t)b * 128 + l + 64];
  __syncthreads();
#pragma unroll
  for (int q = 0; q < 4; ++q) {
    int j = q * 64 + l;
    float acc = 0.f;
    for (int d = 0; d < 128; ++d) acc = fmaf(xs[wv][d], pw1T[d * 256 + j], acc);
    h1s[wv][j] = sigm(acc + pb1[j]);
  }
  __syncthreads();
#pragma unroll
  for (int q = 0; q < 2; ++q) {
    int j = q * 64 + l;
    float acc = 0.f;
    for (int d = 0; d < 256; ++d) acc = fmaf(h1s[wv][d], pw2T[d * 128 + j], acc);
    h2s[wv][j] = sigm(acc + pb2[j]);
  }
  __syncthreads();
  float p = h2s[wv][l] * pw3a[l] + h2s[wv][l + 64] * pw3a[l + 64];
#pragma unroll
  for (int m = 1; m < 64; m <<= 1) p += __shfl_xor(p, m, 64);
  if (l == 0) out[b] = sigm(p + pb3[0]);
}

extern "C" void kernel_launch(void* const* d_in, const int* in_sizes, int n_in,
                              void* d_out, int out_size, void* d_ws, size_t ws_size,
                              hipStream_t stream) {
  const int*   stu_id  = (const int*)  d_in[0];
  const int*   exer_id = (const int*)  d_in[1];
  const float* kn_emb  = (const float*)d_in[2];
  const int*   ui1_u   = (const int*)  d_in[3];
  const int*   ui1_i   = (const int*)  d_in[4];
  const float* ui1_val = (const float*)d_in[5];
  const float* iu1_val = (const float*)d_in[6];
  const float* eps_ui1 = (const float*)d_in[7];
  const float* eps_iu1 = (const float*)d_in[8];
  const int*   ui0_u   = (const int*)  d_in[9];
  const int*   ui0_i   = (const int*)  d_in[10];
  const float* ui0_val = (const float*)d_in[11];
  const float* iu0_val = (const float*)d_in[12];
  const float* eps_ui0 = (const float*)d_in[13];
  const float* eps_iu0 = (const float*)d_in[14];
  const float* stu_emb = (const float*)d_in[15];
  const float* exe_emb = (const float*)d_in[16];
  const float* kno_emb = (const float*)d_in[17];
  const float* stu_b   = (const float*)d_in[18];
  const float* exe_b   = (const float*)d_in[19];
  const float* disc    = (const float*)d_in[20];
  const float* W1_l1   = (const float*)d_in[21];
  const float* b1_l1   = (const float*)d_in[22];
  const float* W2_l1   = (const float*)d_in[23];
  const float* b2_l1   = (const float*)d_in[24];
  const float* W1_l0   = (const float*)d_in[25];
  const float* b1_l0   = (const float*)d_in[26];
  const float* W2_l0   = (const float*)d_in[27];
  const float* b2_l0   = (const float*)d_in[28];
  const float* pw1     = (const float*)d_in[29];
  const float* pb1     = (const float*)d_in[30];
  const float* pw2     = (const float*)d_in[31];
  const float* pb2     = (const float*)d_in[32];
  const float* pw3     = (const float*)d_in[33];
  const float* pb3     = (const float*)d_in[34];
  float* out = (float*)d_out;
  (void)in_sizes; (void)n_in; (void)out_size; (void)ws_size;

  size_t off = 0;
  char* base = (char*)d_ws;
  auto carve = [&](size_t bytes) -> char* {
    char* p = base + off;
    off += (bytes + 255) & ~(size_t)255;
    return p;
  };
  unsigned int* w1f8_1 = (unsigned int*)carve(8192 * 4);
  unsigned int* w1f8_0 = (unsigned int*)carve(8192 * 4);
  float* pw1T = (float*)carve(32768 * 4);
  float* pw2T = (float*)carve(32768 * 4);
  float* pw3a = (float*)carve(128 * 4);
  float* keT  = (float*)carve(16384 * 4);
  // scratch region later used as padded sorted S records (2*NE + BSLACK*NB_S) int2
  char* vblock = carve((size_t)2 * NE_N * 8 + (size_t)BSLACK * NB_S * 8);
  unsigned short* stuBfA = (unsigned short*)carve((size_t)S_N * 128 * 2);
  unsigned short* stuBfB = (unsigned short*)carve((size_t)S_N * 128 * 2);
  unsigned short* exeBfA = (unsigned short*)carve((size_t)E_N * 128 * 2);
  unsigned short* exeBfB = (unsigned short*)carve((size_t)E_N * 128 * 2);
  unsigned int* sf8 = (unsigned int*)carve((size_t)S_N * 32 * 4);
  unsigned int* ef8 = (unsigned int*)carve((size_t)E_N * 32 * 4);
  float* stuS = (float*)carve((size_t)S_N * 128 * 4);
  float* exeS = (float*)carve((size_t)E_N * 128 * 4);
  float* logit1 = (float*)carve((size_t)NE_N * 4);
  float* logit0 = (float*)carve((size_t)NE_N * 4);
  int* gHistS = (int*)carve((size_t)(NB_S + NB_E) * 4);
  int* gHistE = gHistS + NB_S;
  int* baseSb  = (int*)carve((size_t)(NB_S + 1) * 4);
  int* baseEb  = (int*)carve((size_t)(NB_E + 1) * 4);
  int* basePSb = (int*)carve((size_t)(NB_S + 1) * 4);
  int* basePEb = (int*)carve((size_t)(NB_E + 1) * 4);
  int* gCurS  = (int*)carve((size_t)NB_S * 4);
  int* gCurE  = (int*)carve((size_t)NB_E * 4);
  int2* recS = (int2*)carve((size_t)2 * NE_N * 8 + (size_t)BSLACK * NB_E * 8);
  int2* recE = (int2*)carve((size_t)2 * NE_N * 8);
  int* rowPtrS  = (int*)carve((size_t)S_N * 4);
  int* rowCnt8S = (int*)carve((size_t)S_N * 4);
  int* rowPtrE  = (int*)carve((size_t)E_N * 4);
  int* rowCnt8E = (int*)carve((size_t)E_N * 4);
  float* xbuf = (float*)carve((size_t)B_N * 128 * 4);
  int2* rec2S = (int2*)vblock;  // scratch free until sortRow_S
  int2* rec2E = recS;           // recS dead after sortRow_S (stream-ordered)

  prep_kernel<<<(98432 + 255) / 256, 256, 0, stream>>>(W1_l1, W1_l0, pw1, pw2, pw3, kno_emb,
                                                       w1f8_1, w1f8_0, pw1T, pw2T, pw3a, keT);
  init_bf_kernel<<<(2240000 + 255) / 256, 256, 0, stream>>>(stu_emb, exe_emb, stuBfA, exeBfA,
                                                            sf8, ef8, stuS, exeS);
  zero_kernel<<<(NB_S + NB_E + 255) / 256, 256, 0, stream>>>(gHistS, NB_S + NB_E);
  histB_kernel<<<(NE_N + 2047) / 2048, 256, 0, stream>>>(ui1_u, ui1_i, ui0_u, ui0_i,
                                                         gHistS, gHistE);
  scanB_kernel<<<1, 128, 0, stream>>>(gHistS, baseSb, gCurS, basePSb,
                                      gHistE, baseEb, gCurE, basePEb);
  gate_kernel<<<4096, 512, 0, stream>>>(ui1_u, ui1_i, ui0_u, ui0_i,
                                        (const unsigned char*)sf8, (const unsigned char*)ef8,
                                        (const unsigned char*)w1f8_1, (const unsigned char*)w1f8_0,
                                        b1_l1, W2_l1, b2_l1, b1_l0, W2_l0, b2_l0,
                                        logit1, logit0);
  append_kernel<<<(NE_N + 2047) / 2048, 256, 0, stream>>>(ui1_u, ui1_i, ui0_u, ui0_i,
                                                          logit1, logit0,
                                                          ui1_val, iu1_val, eps_ui1, eps_iu1,
                                                          ui0_val, iu0_val, eps_ui0, eps_iu0,
                                                          gCurS, gCurE, recS, recE);
  sortRow_kernel<<<NB_S, 256, 0, stream>>>(baseSb, basePSb, recS, rec2S,
                                           rowPtrS, rowCnt8S, S_N);
  sortRow_kernel<<<NB_E, 256, 0, stream>>>(baseEb, basePEb, recE, rec2E,
                                           rowPtrE, rowCnt8E, E_N);
  const unsigned short* scur = stuBfA; const unsigned short* ecur = exeBfA;
  unsigned short* snxt = stuBfB; unsigned short* enxt = exeBfB;
  for (int layer = 0; layer < L_N; ++layer) {
    spmm_csr_kernel<<<(S_N + E_N + 3) / 4, 256, 0, stream>>>(
        rowPtrS, rowCnt8S, rec2S, rowPtrE, rowCnt8E, rec2E,
        scur, ecur, snxt, enxt, stuS, exeS);
    const unsigned short* t1 = scur; scur = snxt; snxt = (unsigned short*)t1;
    const unsigned short* t2 = ecur; ecur = enxt; enxt = (unsigned short*)t2;
  }
  head1_kernel<<<B_N / 4, 256, 0, stream>>>(stu_id, exer_id, kn_emb, stuS, exeS, keT,
                                            stu_b, exe_b, disc, xbuf);
  head2_kernel<<<B_N / 4, 256, 0, stream>>>(xbuf, pw1T, pb1, pw2T, pb2, pw3a, pb3, out);
}

// Round 16
// 660.006 us; speedup vs baseline: 1.2034x; 1.0499x over previous
//
#include <hip/hip_runtime.h>
#include <hip/hip_bf16.h>
#include <math.h>

#define S_N 50000
#define E_N 20000
#define K_N 128
#define D_N 128
#define NE_N 800000
#define B_N 8192
#define L_N 3
#define GATE_TILES (NE_N / 64)
#define NB_S 782   // ceil(50000/64)
#define NB_E 313   // ceil(20000/64)
#define BPAD 464   // scan reserve base: per bucket p = (v+BPAD+15)&~15 <= v+479
#define BSLACK 480 // allocation slack per bucket (strictly > 479)

typedef __attribute__((ext_vector_type(4))) float floatx4;
typedef __attribute__((ext_vector_type(8))) short short8v;

__device__ __forceinline__ unsigned short f2bf(float x) {
  unsigned int u = __float_as_uint(x);
  u += 0x7FFFu + ((u >> 16) & 1u);
  return (unsigned short)(u >> 16);
}
__device__ __forceinline__ float bf2f(unsigned short u) {
  return __uint_as_float(((unsigned int)u) << 16);
}
__device__ __forceinline__ float sigm(float z) { return 1.0f / (1.0f + __expf(-z)); }

// OCP e4m3fn, round-to-nearest-even, saturating
__device__ __forceinline__ unsigned char f2e4m3(float x) {
  unsigned int u = __float_as_uint(x);
  unsigned char s = (unsigned char)((u >> 24) & 0x80);
  int e = (int)((u >> 23) & 0xFF) - 127;
  unsigned int m = u & 0x7FFFFF;
  if (((u >> 23) & 0xFF) == 0) return s;
  if (e >= 9) return s | 0x7E;
  if (e < -10) return s;
  if (e >= -6) {
    unsigned int keep = m >> 20;
    unsigned int rest = m & 0xFFFFF;
    if (rest > 0x80000u || (rest == 0x80000u && (keep & 1))) keep++;
    if (keep == 8) { keep = 0; e++; if (e >= 9) return s | 0x7E; }
    unsigned char b = (unsigned char)(s | ((e + 7) << 3) | keep);
    if ((b & 0x7F) == 0x7F) b = s | 0x7E;
    return b;
  }
  int shift = -6 - e;
  unsigned int full = 0x800000u | m;
  unsigned int q = full >> (20 + shift);
  unsigned int rest = full & ((1u << (20 + shift)) - 1);
  unsigned int half = 1u << (19 + shift);
  if (rest > half || (rest == half && (q & 1))) q++;
  if (q == 8) return s | 0x08;
  return (unsigned char)(s | q);
}
__device__ __forceinline__ unsigned int pk4_fp8(float4 v) {
  return (unsigned int)f2e4m3(v.x) | ((unsigned int)f2e4m3(v.y) << 8) |
         ((unsigned int)f2e4m3(v.z) << 16) | ((unsigned int)f2e4m3(v.w) << 24);
}

// ---------------- prep: fp8 W1s, |pw|^T, keT ----------------
__global__ void prep_kernel(const float* __restrict__ W1_l1, const float* __restrict__ W1_l0,
                            const float* __restrict__ pw1, const float* __restrict__ pw2,
                            const float* __restrict__ pw3, const float* __restrict__ ke,
                            unsigned int* __restrict__ w1f8_1, unsigned int* __restrict__ w1f8_0,
                            float* __restrict__ pw1T, float* __restrict__ pw2T,
                            float* __restrict__ pw3a, float* __restrict__ keT) {
  int i = blockIdx.x * blockDim.x + threadIdx.x;
  if (i < 8192) { w1f8_1[i] = pk4_fp8(((const float4*)W1_l1)[i]); return; }
  i -= 8192;
  if (i < 8192) { w1f8_0[i] = pk4_fp8(((const float4*)W1_l0)[i]); return; }
  i -= 8192;
  if (i < 32768) { int d = i >> 8, j = i & 255; pw1T[i] = fabsf(pw1[j * 128 + d]); return; }
  i -= 32768;
  if (i < 32768) { int d = i >> 7, j = i & 127; pw2T[i] = fabsf(pw2[j * 256 + d]); return; }
  i -= 32768;
  if (i < 128) { pw3a[i] = fabsf(pw3[i]); return; }
  i -= 128;
  if (i < 16384) { int d = i >> 7, k = i & 127; keT[i] = ke[k * 128 + d]; return; }
}

// ---------------- init: bf16 tables (spmm L0) + fp8 tables (gate) ----------------
__global__ void init_bf_kernel(const float* __restrict__ se, const float* __restrict__ ee,
                               unsigned short* __restrict__ sbf, unsigned short* __restrict__ ebf,
                               unsigned int* __restrict__ sf8, unsigned int* __restrict__ ef8) {
  int i = blockIdx.x * blockDim.x + threadIdx.x;
  const int nS4 = S_N * 32, nE4 = E_N * 32;
  if (i < nS4) {
    float4 v = ((const float4*)se)[i];
    unsigned int lo = (unsigned int)f2bf(v.x) | ((unsigned int)f2bf(v.y) << 16);
    unsigned int hi = (unsigned int)f2bf(v.z) | ((unsigned int)f2bf(v.w) << 16);
    ((uint2*)sbf)[i] = make_uint2(lo, hi);
    sf8[i] = pk4_fp8(v);
    return;
  }
  i -= nS4;
  if (i < nE4) {
    float4 v = ((const float4*)ee)[i];
    unsigned int lo = (unsigned int)f2bf(v.x) | ((unsigned int)f2bf(v.y) << 16);
    unsigned int hi = (unsigned int)f2bf(v.z) | ((unsigned int)f2bf(v.w) << 16);
    ((uint2*)ebf)[i] = make_uint2(lo, hi);
    ef8[i] = pk4_fp8(v);
  }
}

__global__ void zero_kernel(int* __restrict__ p, int n) {
  int i = blockIdx.x * blockDim.x + threadIdx.x;
  if (i < n) p[i] = 0;
}

// ---------------- bucket histogram (64-row buckets) ----------------
__global__ __launch_bounds__(256)
void histB_kernel(const int* __restrict__ u1, const int* __restrict__ i1,
                  const int* __restrict__ u0, const int* __restrict__ i0,
                  int* __restrict__ gHistS, int* __restrict__ gHistE) {
  __shared__ int hS[NB_S], hE[NB_E];
  int t = threadIdx.x;
  for (int b = t; b < NB_S; b += 256) hS[b] = 0;
  for (int b = t; b < NB_E; b += 256) hE[b] = 0;
  __syncthreads();
  int e0 = blockIdx.x * 2048;
  for (int k = 0; k < 8; ++k) {
    int e = e0 + k * 256 + t;
    if (e < NE_N) {
      atomicAdd(&hS[u1[e] >> 6], 1);
      atomicAdd(&hS[u0[e] >> 6], 1);
      atomicAdd(&hE[i1[e] >> 6], 1);
      atomicAdd(&hE[i0[e] >> 6], 1);
    }
  }
  __syncthreads();
  for (int b = t; b < NB_S; b += 256) if (hS[b]) atomicAdd(&gHistS[b], hS[b]);
  for (int b = t; b < NB_E; b += 256) if (hE[b]) atomicAdd(&gHistE[b], hE[b]);
}

// ------- scan buckets: packed bases+cursors AND padded-region bases -------
__global__ __launch_bounds__(128)
void scanB_kernel(const int* __restrict__ gHistS, int* __restrict__ baseS,
                  int* __restrict__ gCurS, int* __restrict__ basePS,
                  const int* __restrict__ gHistE, int* __restrict__ baseE,
                  int* __restrict__ gCurE, int* __restrict__ basePE) {
  int w = threadIdx.x >> 6, l = threadIdx.x & 63;
  int n = w ? NB_E : NB_S;
  const int* src = w ? gHistE : gHistS;
  int* bs  = w ? baseE  : baseS;
  int* cur = w ? gCurE  : gCurS;
  int* bsP = w ? basePE : basePS;
  int carry = 0, carryP = 0;
  for (int base = 0; base < n; base += 64) {
    int i = base + l;
    int v = (i < n) ? src[i] : 0;
    int p = (i < n) ? ((v + BPAD + 15) & ~15) : 0;
    int x = v, y = p;
#pragma unroll
    for (int o = 1; o < 64; o <<= 1) {
      int xx = __shfl_up(x, o, 64);
      int yy = __shfl_up(y, o, 64);
      if (l >= o) { x += xx; y += yy; }
    }
    if (i < n) {
      int ex = carry + x - v;
      bs[i] = ex; cur[i] = ex;
      bsP[i] = carryP + y - p;
    }
    carry += __shfl(x, 63, 64);
    carryP += __shfl(y, 63, 64);
  }
  if (l == 0) { bs[n] = carry; bsP[n] = carryP; }
}

// ------- edge gate: merged polarities, DOUBLE-BUFFERED (T14 async-stage) -------
__global__ __launch_bounds__(512, 2)
void gate_kernel(const int* __restrict__ eu1, const int* __restrict__ ei1,
                 const int* __restrict__ eu0, const int* __restrict__ ei0,
                 const unsigned char* __restrict__ sf8, const unsigned char* __restrict__ ef8,
                 const unsigned char* __restrict__ w1f8_1, const unsigned char* __restrict__ w1f8_0,
                 const float* __restrict__ b1_1, const float* __restrict__ w2_1,
                 const float* __restrict__ b2_1,
                 const float* __restrict__ b1_0, const float* __restrict__ w2_0,
                 const float* __restrict__ b2_0,
                 float* __restrict__ logit1, float* __restrict__ logit0) {
  __shared__ unsigned char Xl[2][64 * 272];
  __shared__ float plds[8][16];
  const int* eu; const int* ei; const unsigned char* w1f8;
  const float *b1p, *w2p, *b2p; float* lg;
  if (blockIdx.x < 2048) {
    eu = eu1; ei = ei1; w1f8 = w1f8_1; b1p = b1_1; w2p = w2_1; b2p = b2_1; lg = logit1;
  } else {
    eu = eu0; ei = ei0; w1f8 = w1f8_0; b1p = b1_0; w2p = w2_0; b2p = b2_0; lg = logit0;
  }
  int bb = blockIdx.x & 2047;
  int t = threadIdx.x;
  int wv = t >> 6, l = t & 63;
  int sub = l & 15, grp = l >> 4;
  int nh = wv & 1, rg = wv >> 1;
  int el = t >> 3, q = t & 7;

  long bfrag[4][8];
#pragma unroll
  for (int nt = 0; nt < 4; ++nt) {
    int col = nh * 64 + nt * 16 + sub;
#pragma unroll
    for (int ks = 0; ks < 8; ++ks)
      bfrag[nt][ks] = *(const long*)&w1f8[(col << 8) + ks * 32 + grp * 8];
  }
  float b1v[4], w2v[4];
#pragma unroll
  for (int nt = 0; nt < 4; ++nt) {
    int col = nh * 64 + nt * 16 + sub;
    b1v[nt] = b1p[col];
    w2v[nt] = w2p[col];
  }
  float b2s = b2p[0];

  uint4 c0, c1;
  {  // prologue: stage tile bb into buffer 0
    int eIdx = bb * 64 + el;
    const unsigned char* srcrow = (q < 4)
        ? sf8 + (size_t)eu[eIdx] * 128 + q * 32
        : ef8 + (size_t)ei[eIdx] * 128 + (q - 4) * 32;
    c0 = ((const uint4*)srcrow)[0];
    c1 = ((const uint4*)srcrow)[1];
    *(uint4*)&Xl[0][el * 272 + q * 32] = c0;
    *(uint4*)&Xl[0][el * 272 + q * 32 + 16] = c1;
  }
  int parity = 0;
  for (int tile = bb; tile < GATE_TILES; tile += 2048) {
    int nxt = tile + 2048;
    bool hasNext = (nxt < GATE_TILES);
    if (hasNext) {  // issue next tile's gathers early: latency hides under MFMA below
      int eIdx = nxt * 64 + el;
      const unsigned char* srcrow = (q < 4)
          ? sf8 + (size_t)eu[eIdx] * 128 + q * 32
          : ef8 + (size_t)ei[eIdx] * 128 + (q - 4) * 32;
      c0 = ((const uint4*)srcrow)[0];
      c1 = ((const uint4*)srcrow)[1];
    }
    __syncthreads();   // Xl[parity] fully staged

    floatx4 zero4 = {0.f, 0.f, 0.f, 0.f};
    floatx4 acc[4] = {zero4, zero4, zero4, zero4};
#pragma unroll
    for (int ks = 0; ks < 8; ++ks) {
      long a = *(const long*)&Xl[parity][(rg * 16 + sub) * 272 + ks * 32 + grp * 8];
#pragma unroll
      for (int nt = 0; nt < 4; ++nt)
        acc[nt] = __builtin_amdgcn_mfma_f32_16x16x32_fp8_fp8(a, bfrag[nt][ks], acc[nt], 0, 0, 0);
    }
    float p0 = 0, p1 = 0, p2 = 0, p3 = 0;
#pragma unroll
    for (int nt = 0; nt < 4; ++nt) {
      float bb2 = b1v[nt], ww = w2v[nt];
      p0 += fmaxf(acc[nt][0] + bb2, 0.0f) * ww;
      p1 += fmaxf(acc[nt][1] + bb2, 0.0f) * ww;
      p2 += fmaxf(acc[nt][2] + bb2, 0.0f) * ww;
      p3 += fmaxf(acc[nt][3] + bb2, 0.0f) * ww;
    }
#pragma unroll
    for (int m = 1; m < 16; m <<= 1) {
      p0 += __shfl_xor(p0, m, 64);
      p1 += __shfl_xor(p1, m, 64);
      p2 += __shfl_xor(p2, m, 64);
      p3 += __shfl_xor(p3, m, 64);
    }
    if (sub < 4) {
      float pv = (sub == 0) ? p0 : (sub == 1) ? p1 : (sub == 2) ? p2 : p3;
      plds[wv][grp * 4 + sub] = pv;
    }
    __syncthreads();   // plds ready; all reads of Xl[parity] done
    if (wv == 0)
      lg[tile * 64 + l] = plds[(l >> 4) * 2][l & 15] + plds[(l >> 4) * 2 + 1][l & 15] + b2s;
    if (hasNext) {     // write staged regs into the other buffer (its readers finished last iter)
      *(uint4*)&Xl[parity ^ 1][el * 272 + q * 32] = c0;
      *(uint4*)&Xl[parity ^ 1][el * 272 + q * 32 + 16] = c1;
    }
    parity ^= 1;
  }
}

// ------- append (gatefin FUSED): compute v inline from logit/eps/val, bucket-append -------
__global__ __launch_bounds__(256)
void append_kernel(const int* __restrict__ u1, const int* __restrict__ i1,
                   const int* __restrict__ u0, const int* __restrict__ i0,
                   const float* __restrict__ logit1, const float* __restrict__ logit0,
                   const float* __restrict__ ui1_val, const float* __restrict__ iu1_val,
                   const float* __restrict__ eps_ui1, const float* __restrict__ eps_iu1,
                   const float* __restrict__ ui0_val, const float* __restrict__ iu0_val,
                   const float* __restrict__ eps_ui0, const float* __restrict__ eps_iu0,
                   int* __restrict__ gCurS, int* __restrict__ gCurE,
                   int2* __restrict__ recS, int2* __restrict__ recE) {
  __shared__ int hS[NB_S], hE[NB_E];
  int t = threadIdx.x;
  for (int b = t; b < NB_S; b += 256) hS[b] = 0;
  for (int b = t; b < NB_E; b += 256) hE[b] = 0;
  __syncthreads();
  int e0 = blockIdx.x * 2048;
  for (int k = 0; k < 8; ++k) {
    int e = e0 + k * 256 + t;
    if (e < NE_N) {
      atomicAdd(&hS[u1[e] >> 6], 1);
      atomicAdd(&hS[u0[e] >> 6], 1);
      atomicAdd(&hE[i1[e] >> 6], 1);
      atomicAdd(&hE[i0[e] >> 6], 1);
    }
  }
  __syncthreads();
  for (int b = t; b < NB_S; b += 256) { int c = hS[b]; hS[b] = c ? atomicAdd(&gCurS[b], c) : 0; }
  for (int b = t; b < NB_E; b += 256) { int c = hE[b]; hE[b] = c ? atomicAdd(&gCurE[b], c) : 0; }
  __syncthreads();
  for (int k = 0; k < 8; ++k) {
    int e = e0 + k * 256 + t;
    if (e < NE_N) {
      int a = u1[e], b = i1[e], c = u0[e], d = i0[e];
      float lg1 = logit1[e], lg0 = logit0[e];
      float ep, g, s2;
      ep = fminf(fmaxf(eps_ui1[e], 1e-6f), 1.0f - 1e-6f);
      g = __logf(ep) - log1pf(-ep);
      s2 = 1.0f / (1.0f + __expf(-(lg1 + g) * 5.0f));
      float v_ui1 = ui1_val[e] * (0.3f * s2 + 0.7f);
      ep = fminf(fmaxf(eps_iu1[e], 1e-6f), 1.0f - 1e-6f);
      g = __logf(ep) - log1pf(-ep);
      s2 = 1.0f / (1.0f + __expf(-(lg1 + g) * 5.0f));
      float v_iu1 = iu1_val[e] * (0.3f * s2 + 0.7f);
      ep = fminf(fmaxf(eps_ui0[e], 1e-6f), 1.0f - 1e-6f);
      g = __logf(ep) - log1pf(-ep);
      s2 = 1.0f / (1.0f + __expf(-(lg0 + g) * 5.0f));
      float v_ui0 = ui0_val[e] * (0.3f * s2 + 0.7f);
      ep = fminf(fmaxf(eps_iu0[e], 1e-6f), 1.0f - 1e-6f);
      g = __logf(ep) - log1pf(-ep);
      s2 = 1.0f / (1.0f + __expf(-(lg0 + g) * 5.0f));
      float v_iu0 = iu0_val[e] * (0.3f * s2 + 0.7f);
      int s;
      s = atomicAdd(&hS[a >> 6], 1); recS[s] = make_int2(((a & 63) << 16) | b, __float_as_int(v_ui1));
      s = atomicAdd(&hE[b >> 6], 1); recE[s] = make_int2(((b & 63) << 16) | a, __float_as_int(v_iu1));
      s = atomicAdd(&hS[c >> 6], 1); recS[s] = make_int2(((c & 63) << 16) | d, __float_as_int(v_ui0));
      s = atomicAdd(&hE[d >> 6], 1); recE[s] = make_int2(((d & 63) << 16) | c, __float_as_int(v_iu0));
    }
  }
}

// ---- per-bucket counting sort by dst ROW into padded per-row segments (once) ----
__global__ __launch_bounds__(256)
void sortRow_kernel(const int* __restrict__ baseIn, const int* __restrict__ basePad,
                    const int2* __restrict__ rin_all, int2* __restrict__ rout_all,
                    int* __restrict__ rowPtr, int* __restrict__ rowCnt8, int nRowsTot) {
  __shared__ int cntR[64], offR[64], curR[64];
  int b = blockIdx.x, t = threadIdx.x;
  int bi = baseIn[b], cnt = baseIn[b + 1] - bi;
  int bo = basePad[b];
  int row0 = b * 64;
  const int2* rin = rin_all + bi;
  int2* rout = rout_all + bo;
  if (t < 64) cntR[t] = 0;
  __syncthreads();
  for (int j = t; j < cnt; j += 256) atomicAdd(&cntR[(rin[j].x >> 16) & 63], 1);
  __syncthreads();
  if (t < 64) {
    int p = (cntR[t] + 7) & ~7;
    int x = p;
#pragma unroll
    for (int o = 1; o < 64; o <<= 1) { int y = __shfl_up(x, o, 64); if (t >= o) x += y; }
    int ex = x - p;
    offR[t] = ex; curR[t] = ex;
    if (row0 + t < nRowsTot) {
      rowPtr[row0 + t] = bo + ex;
      rowCnt8[row0 + t] = p >> 3;
    }
  }
  __syncthreads();
  for (int j = t; j < cnt; j += 256) {
    int2 rc = rin[j];
    int r = (rc.x >> 16) & 63;
    int slot = atomicAdd(&curR[r], 1);
    rout[slot] = make_int2(rc.x & 0xFFFF, rc.y);
  }
  __syncthreads();
  if (t < 64) {
    int c = cntR[t], p = (c + 7) & ~7, o = offR[t];
    for (int j = c; j < p; ++j) rout[o + j] = make_int2(0, 0);
  }
}

// ---- spmm CSR bf16: wave per dst row, 8 records in flight; NO sum RMW (layer outputs kept) ----
__global__ __launch_bounds__(256)
void spmm_csr_kernel(const int* __restrict__ rowPtrS, const int* __restrict__ rowCnt8S,
                     const int2* __restrict__ rec2S,
                     const int* __restrict__ rowPtrE, const int* __restrict__ rowCnt8E,
                     const int2* __restrict__ rec2E,
                     const unsigned short* __restrict__ scur, const unsigned short* __restrict__ ecur,
                     unsigned short* __restrict__ snxt, unsigned short* __restrict__ enxt) {
  int gw = (blockIdx.x * 256 + threadIdx.x) >> 6;
  int l = threadIdx.x & 63;
  int g = l >> 3, lane8 = l & 7;
  if (gw >= S_N + E_N) return;
  const int2* rec; const unsigned short* src; unsigned short* dst;
  const int* rp; const int* rc8; int r;
  if (gw < S_N) { r = gw;       rp = rowPtrS; rc8 = rowCnt8S; rec = rec2S; src = ecur; dst = snxt; }
  else          { r = gw - S_N; rp = rowPtrE; rc8 = rowCnt8E; rec = rec2E; src = scur; dst = enxt; }
  int s0 = rp[r], n8 = rc8[r];
  float acc[16];
#pragma unroll
  for (int i = 0; i < 16; ++i) acc[i] = 0.f;
  for (int k = 0; k < n8; ++k) {
    int2 e = rec[s0 + k * 8 + g];
    float val = __int_as_float(e.y);
    const uint4* rowp = (const uint4*)(src + (size_t)e.x * 128);
    uint4 q0 = rowp[lane8 * 2];
    uint4 q1 = rowp[lane8 * 2 + 1];
#pragma unroll
    for (int i = 0; i < 4; ++i) {
      unsigned int w = ((const unsigned int*)&q0)[i];
      acc[2 * i]     = fmaf(val, bf2f((unsigned short)(w & 0xFFFF)), acc[2 * i]);
      acc[2 * i + 1] = fmaf(val, bf2f((unsigned short)(w >> 16)),    acc[2 * i + 1]);
    }
#pragma unroll
    for (int i = 0; i < 4; ++i) {
      unsigned int w = ((const unsigned int*)&q1)[i];
      acc[8 + 2 * i]     = fmaf(val, bf2f((unsigned short)(w & 0xFFFF)), acc[8 + 2 * i]);
      acc[8 + 2 * i + 1] = fmaf(val, bf2f((unsigned short)(w >> 16)),    acc[8 + 2 * i + 1]);
    }
  }
#pragma unroll
  for (int m = 8; m < 64; m <<= 1) {
#pragma unroll
    for (int i = 0; i < 16; ++i) acc[i] += __shfl_xor(acc[i], m, 64);
  }
  if (g == 0) {
    size_t base = (size_t)r * 128 + lane8 * 16;
    short8v o0, o1;
#pragma unroll
    for (int i = 0; i < 8; ++i) { o0[i] = (short)f2bf(acc[i]); o1[i] = (short)f2bf(acc[8 + i]); }
    *(short8v*)(dst + base) = o0;
    *(short8v*)(dst + base + 8) = o1;
  }
}

// ------- head 1: gather-sum 4 bf16 layer tables per side (replaces f32 sum tables) -------
__global__ __launch_bounds__(256)
void head1_kernel(const int* __restrict__ stu_id, const int* __restrict__ exer_id,
                  const float* __restrict__ kn,
                  const unsigned short* __restrict__ sT0, const unsigned short* __restrict__ sT1,
                  const unsigned short* __restrict__ sT2, const unsigned short* __restrict__ sT3,
                  const unsigned short* __restrict__ eT0, const unsigned short* __restrict__ eT1,
                  const unsigned short* __restrict__ eT2, const unsigned short* __restrict__ eT3,
                  const float* __restrict__ keT,
                  const float* __restrict__ stub, const float* __restrict__ exeb,
                  const float* __restrict__ disc, float* __restrict__ xbuf) {
  __shared__ float srw[4][128], erw[4][128];
  int wv = threadIdx.x >> 6, l = threadIdx.x & 63;
  int b = blockIdx.x * 4 + wv;
  int sid = stu_id[b], eid = exer_id[b];
  size_t so = (size_t)sid * 128, eo = (size_t)eid * 128;
  float sx = 0.f, sy = 0.f, ex = 0.f, ey = 0.f;
  unsigned int w;
  w = ((const unsigned int*)(sT0 + so))[l]; sx += bf2f((unsigned short)(w & 0xFFFF)); sy += bf2f((unsigned short)(w >> 16));
  w = ((const unsigned int*)(sT1 + so))[l]; sx += bf2f((unsigned short)(w & 0xFFFF)); sy += bf2f((unsigned short)(w >> 16));
  w = ((const unsigned int*)(sT2 + so))[l]; sx += bf2f((unsigned short)(w & 0xFFFF)); sy += bf2f((unsigned short)(w >> 16));
  w = ((const unsigned int*)(sT3 + so))[l]; sx += bf2f((unsigned short)(w & 0xFFFF)); sy += bf2f((unsigned short)(w >> 16));
  w = ((const unsigned int*)(eT0 + eo))[l]; ex += bf2f((unsigned short)(w & 0xFFFF)); ey += bf2f((unsigned short)(w >> 16));
  w = ((const unsigned int*)(eT1 + eo))[l]; ex += bf2f((unsigned short)(w & 0xFFFF)); ey += bf2f((unsigned short)(w >> 16));
  w = ((const unsigned int*)(eT2 + eo))[l]; ex += bf2f((unsigned short)(w & 0xFFFF)); ey += bf2f((unsigned short)(w >> 16));
  w = ((const unsigned int*)(eT3 + eo))[l]; ex += bf2f((unsigned short)(w & 0xFFFF)); ey += bf2f((unsigned short)(w >> 16));
  srw[wv][2 * l] = sx * 0.25f; srw[wv][2 * l + 1] = sy * 0.25f;
  erw[wv][2 * l] = ex * 0.25f; erw[wv][2 * l + 1] = ey * 0.25f;
  __syncthreads();
  float s0 = 0, s1 = 0, d0 = 0, d1 = 0;
  for (int d = 0; d < 128; ++d) {
    float sd = srw[wv][d], ed = erw[wv][d];
    float ka = keT[d * 128 + l], kb = keT[d * 128 + l + 64];
    s0 = fmaf(sd, ka, s0); s1 = fmaf(sd, kb, s1);
    d0 = fmaf(ed, ka, d0); d1 = fmaf(ed, kb, d1);
  }
  float sbv = stub[sid], ebv = exeb[eid];
  float edv = sigm(disc[eid]);
  float st0 = sigm(s0 + sbv), st1 = sigm(s1 + sbv);
  float df0 = sigm(d0 + ebv), df1 = sigm(d1 + ebv);
  xbuf[(size_t)b * 128 + l]      = edv * (st0 - df0) * kn[(size_t)b * 128 + l];
  xbuf[(size_t)b * 128 + l + 64] = edv * (st1 - df1) * kn[(size_t)b * 128 + l + 64];
}

// ---------------- head 2: PosLinear MLP ----------------
__global__ __launch_bounds__(256)
void head2_kernel(const float* __restrict__ xbuf, const float* __restrict__ pw1T,
                  const float* __restrict__ pb1, const float* __restrict__ pw2T,
                  const float* __restrict__ pb2, const float* __restrict__ pw3a,
                  const float* __restrict__ pb3, float* __restrict__ out) {
  __shared__ float xs[4][128], h1s[4][256], h2s[4][128];
  int wv = threadIdx.x >> 6, l = threadIdx.x & 63;
  int b = blockIdx.x * 4 + wv;
  xs[wv][l] = xbuf[(size_t)b * 128 + l];
  xs[wv][l + 64] = xbuf[(size_t)b * 128 + l + 64];
  __syncthreads();
#pragma unroll
  for (int q = 0; q < 4; ++q) {
    int j = q * 64 + l;
    float acc = 0.f;
    for (int d = 0; d < 128; ++d) acc = fmaf(xs[wv][d], pw1T[d * 256 + j], acc);
    h1s[wv][j] = sigm(acc + pb1[j]);
  }
  __syncthreads();
#pragma unroll
  for (int q = 0; q < 2; ++q) {
    int j = q * 64 + l;
    float acc = 0.f;
    for (int d = 0; d < 256; ++d) acc = fmaf(h1s[wv][d], pw2T[d * 128 + j], acc);
    h2s[wv][j] = sigm(acc + pb2[j]);
  }
  __syncthreads();
  float p = h2s[wv][l] * pw3a[l] + h2s[wv][l + 64] * pw3a[l + 64];
#pragma unroll
  for (int m = 1; m < 64; m <<= 1) p += __shfl_xor(p, m, 64);
  if (l == 0) out[b] = sigm(p + pb3[0]);
}

extern "C" void kernel_launch(void* const* d_in, const int* in_sizes, int n_in,
                              void* d_out, int out_size, void* d_ws, size_t ws_size,
                              hipStream_t stream) {
  const int*   stu_id  = (const int*)  d_in[0];
  const int*   exer_id = (const int*)  d_in[1];
  const float* kn_emb  = (const float*)d_in[2];
  const int*   ui1_u   = (const int*)  d_in[3];
  const int*   ui1_i   = (const int*)  d_in[4];
  const float* ui1_val = (const float*)d_in[5];
  const float* iu1_val = (const float*)d_in[6];
  const float* eps_ui1 = (const float*)d_in[7];
  const float* eps_iu1 = (const float*)d_in[8];
  const int*   ui0_u   = (const int*)  d_in[9];
  const int*   ui0_i   = (const int*)  d_in[10];
  const float* ui0_val = (const float*)d_in[11];
  const float* iu0_val = (const float*)d_in[12];
  const float* eps_ui0 = (const float*)d_in[13];
  const float* eps_iu0 = (const float*)d_in[14];
  const float* stu_emb = (const float*)d_in[15];
  const float* exe_emb = (const float*)d_in[16];
  const float* kno_emb = (const float*)d_in[17];
  const float* stu_b   = (const float*)d_in[18];
  const float* exe_b   = (const float*)d_in[19];
  const float* disc    = (const float*)d_in[20];
  const float* W1_l1   = (const float*)d_in[21];
  const float* b1_l1   = (const float*)d_in[22];
  const float* W2_l1   = (const float*)d_in[23];
  const float* b2_l1   = (const float*)d_in[24];
  const float* W1_l0   = (const float*)d_in[25];
  const float* b1_l0   = (const float*)d_in[26];
  const float* W2_l0   = (const float*)d_in[27];
  const float* b2_l0   = (const float*)d_in[28];
  const float* pw1     = (const float*)d_in[29];
  const float* pb1     = (const float*)d_in[30];
  const float* pw2     = (const float*)d_in[31];
  const float* pb2     = (const float*)d_in[32];
  const float* pw3     = (const float*)d_in[33];
  const float* pb3     = (const float*)d_in[34];
  float* out = (float*)d_out;
  (void)in_sizes; (void)n_in; (void)out_size; (void)ws_size;

  size_t off = 0;
  char* base = (char*)d_ws;
  auto carve = [&](size_t bytes) -> char* {
    char* p = base + off;
    off += (bytes + 255) & ~(size_t)255;
    return p;
  };
  unsigned int* w1f8_1 = (unsigned int*)carve(8192 * 4);
  unsigned int* w1f8_0 = (unsigned int*)carve(8192 * 4);
  float* pw1T = (float*)carve(32768 * 4);
  float* pw2T = (float*)carve(32768 * 4);
  float* pw3a = (float*)carve(128 * 4);
  float* keT  = (float*)carve(16384 * 4);
  // scratch region later used as padded sorted S records (2*NE + BSLACK*NB_S) int2
  char* vblock = carve((size_t)2 * NE_N * 8 + (size_t)BSLACK * NB_S * 8);
  // 4-deep bf16 layer tables (L0..L3) per side
  unsigned short* stuT0 = (unsigned short*)carve((size_t)S_N * 128 * 2);
  unsigned short* stuT1 = (unsigned short*)carve((size_t)S_N * 128 * 2);
  unsigned short* stuT2 = (unsigned short*)carve((size_t)S_N * 128 * 2);
  unsigned short* stuT3 = (unsigned short*)carve((size_t)S_N * 128 * 2);
  unsigned short* exeT0 = (unsigned short*)carve((size_t)E_N * 128 * 2);
  unsigned short* exeT1 = (unsigned short*)carve((size_t)E_N * 128 * 2);
  unsigned short* exeT2 = (unsigned short*)carve((size_t)E_N * 128 * 2);
  unsigned short* exeT3 = (unsigned short*)carve((size_t)E_N * 128 * 2);
  unsigned int* sf8 = (unsigned int*)carve((size_t)S_N * 32 * 4);
  unsigned int* ef8 = (unsigned int*)carve((size_t)E_N * 32 * 4);
  float* logit1 = (float*)carve((size_t)NE_N * 4);
  float* logit0 = (float*)carve((size_t)NE_N * 4);
  int* gHistS = (int*)carve((size_t)(NB_S + NB_E) * 4);
  int* gHistE = gHistS + NB_S;
  int* baseSb  = (int*)carve((size_t)(NB_S + 1) * 4);
  int* baseEb  = (int*)carve((size_t)(NB_E + 1) * 4);
  int* basePSb = (int*)carve((size_t)(NB_S + 1) * 4);
  int* basePEb = (int*)carve((size_t)(NB_E + 1) * 4);
  int* gCurS  = (int*)carve((size_t)NB_S * 4);
  int* gCurE  = (int*)carve((size_t)NB_E * 4);
  int2* recS = (int2*)carve((size_t)2 * NE_N * 8 + (size_t)BSLACK * NB_E * 8);
  int2* recE = (int2*)carve((size_t)2 * NE_N * 8);
  int* rowPtrS  = (int*)carve((size_t)S_N * 4);
  int* rowCnt8S = (int*)carve((size_t)S_N * 4);
  int* rowPtrE  = (int*)carve((size_t)E_N * 4);
  int* rowCnt8E = (int*)carve((size_t)E_N * 4);
  float* xbuf = (float*)carve((size_t)B_N * 128 * 4);
  int2* rec2S = (int2*)vblock;  // scratch free until sortRow_S
  int2* rec2E = recS;           // recS dead after sortRow_S (stream-ordered)

  prep_kernel<<<(98432 + 255) / 256, 256, 0, stream>>>(W1_l1, W1_l0, pw1, pw2, pw3, kno_emb,
                                                       w1f8_1, w1f8_0, pw1T, pw2T, pw3a, keT);
  init_bf_kernel<<<(2240000 + 255) / 256, 256, 0, stream>>>(stu_emb, exe_emb, stuT0, exeT0,
                                                            sf8, ef8);
  zero_kernel<<<(NB_S + NB_E + 255) / 256, 256, 0, stream>>>(gHistS, NB_S + NB_E);
  histB_kernel<<<(NE_N + 2047) / 2048, 256, 0, stream>>>(ui1_u, ui1_i, ui0_u, ui0_i,
                                                         gHistS, gHistE);
  scanB_kernel<<<1, 128, 0, stream>>>(gHistS, baseSb, gCurS, basePSb,
                                      gHistE, baseEb, gCurE, basePEb);
  gate_kernel<<<4096, 512, 0, stream>>>(ui1_u, ui1_i, ui0_u, ui0_i,
                                        (const unsigned char*)sf8, (const unsigned char*)ef8,
                                        (const unsigned char*)w1f8_1, (const unsigned char*)w1f8_0,
                                        b1_l1, W2_l1, b2_l1, b1_l0, W2_l0, b2_l0,
                                        logit1, logit0);
  append_kernel<<<(NE_N + 2047) / 2048, 256, 0, stream>>>(ui1_u, ui1_i, ui0_u, ui0_i,
                                                          logit1, logit0,
                                                          ui1_val, iu1_val, eps_ui1, eps_iu1,
                                                          ui0_val, iu0_val, eps_ui0, eps_iu0,
                                                          gCurS, gCurE, recS, recE);
  sortRow_kernel<<<NB_S, 256, 0, stream>>>(baseSb, basePSb, recS, rec2S,
                                           rowPtrS, rowCnt8S, S_N);
  sortRow_kernel<<<NB_E, 256, 0, stream>>>(baseEb, basePEb, recE, rec2E,
                                           rowPtrE, rowCnt8E, E_N);
  unsigned short* stuT[4] = {stuT0, stuT1, stuT2, stuT3};
  unsigned short* exeT[4] = {exeT0, exeT1, exeT2, exeT3};
  for (int layer = 0; layer < L_N; ++layer) {
    spmm_csr_kernel<<<(S_N + E_N + 3) / 4, 256, 0, stream>>>(
        rowPtrS, rowCnt8S, rec2S, rowPtrE, rowCnt8E, rec2E,
        stuT[layer], exeT[layer], stuT[layer + 1], exeT[layer + 1]);
  }
  head1_kernel<<<B_N / 4, 256, 0, stream>>>(stu_id, exer_id, kn_emb,
                                            stuT0, stuT1, stuT2, stuT3,
                                            exeT0, exeT1, exeT2, exeT3,
                                            keT, stu_b, exe_b, disc, xbuf);
  head2_kernel<<<B_N / 4, 256, 0, stream>>>(xbuf, pw1T, pb1, pw2T, pb2, pw3a, pb3, out);
}